// Round 1
// baseline (741.112 us; speedup 1.0000x reference)
//
#include <hip/hip_runtime.h>
#include <cstddef>
#include <cstdint>

// B=8, C=2, Hf=257, T=2048, D_IN=514, DM=256, NL=4, N=32
// Activations: fp32 planes (b, 2*DM=512, T). GEMMs run bf16 MFMA with
// k-major bf16 activation copies (b, T, Kp).

typedef __attribute__((ext_vector_type(8))) short short8;
typedef __attribute__((ext_vector_type(4))) float float4v;

__device__ __forceinline__ unsigned short f2bf(float f) {
    union { float f; unsigned u; } v; v.f = f;
    const unsigned r = v.u + 0x7fffu + ((v.u >> 16) & 1u);  // RNE
    return (unsigned short)(r >> 16);
}

__device__ __forceinline__ float gelu_tanh(float x) {
    const float x3 = x * x * x;
    const float v  = 0.7978845608028654f * (x + 0.044715f * x3);
    const float e  = __expf(2.f * v);
    const float th = 1.f - 2.f / (e + 1.f);
    return 0.5f * x * (1.f + th);
}

#define ASYNC_COPY16(gp, lp) __builtin_amdgcn_global_load_lds( \
    (const __attribute__((address_space(1))) unsigned int*)(gp), \
    (__attribute__((address_space(3))) unsigned int*)(lp), 16, 0, 0)

// ---------- builders: bf16 real-rep of complex weights, padded ----------
__global__ __launch_bounds__(256) void buildw_k(
    const float* __restrict__ Wr, const float* __restrict__ Wi,
    unsigned short* __restrict__ A, int G, int H, int Hoff, int Kp, int Mp)
{
    const long long i = (long long)blockIdx.x * 256 + threadIdx.x;
    if (i >= (long long)Mp * Kp) return;
    const int m = (int)(i / Kp), k = (int)(i % Kp);
    float val = 0.f;
    if (m < 2 * G) {
        const int ri = m >= G;
        const int g = m - ri * G;
        const int blk = k >= Hoff;
        const int hh = k - blk * Hoff;
        if (hh < H) {
            const float wr = Wr[(size_t)g * H + hh];
            const float wi = Wi[(size_t)g * H + hh];
            val = ri ? (blk ? wr : wi) : (blk ? -wi : wr);
        }
    }
    A[i] = f2bf(val);
}

__global__ __launch_bounds__(256) void build_bias_k(
    const float* __restrict__ br, const float* __restrict__ bi,
    float* __restrict__ bias, int G)
{
    const int i = blockIdx.x * 256 + threadIdx.x;
    if (i < G) bias[i] = br[i];
    else if (i < 2 * G) bias[i] = bi[i - G];
}

// ---------- encoder input pack: x (b,514,T,2) fp32 -> xp (b,T,1056) bf16 ----------
__global__ __launch_bounds__(256) void packx_k(const float* __restrict__ x,
                                               unsigned short* __restrict__ xp)
{
    const int t0 = blockIdx.x * 64, d0 = blockIdx.y * 64, b = blockIdx.z;
    __shared__ unsigned short tr_[64][72];
    __shared__ unsigned short ti_[64][72];
    const int tid = threadIdx.x;
    const int tp = tid & 31, dl0 = tid >> 5;
#pragma unroll
    for (int p = 0; p < 8; ++p) {
        const int d = dl0 + p * 8;
        const int gd = d0 + d;
        float4 v = make_float4(0.f, 0.f, 0.f, 0.f);
        if (gd < 514) v = *(const float4*)(x + (((size_t)b * 514 + gd) * 2048 + t0 + tp * 2) * 2);
        tr_[tp * 2 + 0][d] = f2bf(v.x); ti_[tp * 2 + 0][d] = f2bf(v.y);
        tr_[tp * 2 + 1][d] = f2bf(v.z); ti_[tp * 2 + 1][d] = f2bf(v.w);
    }
    __syncthreads();
    const int dc = tid & 7;
    const int kloc = d0 + dc * 8;
    if (kloc < 528) {
#pragma unroll
        for (int p = 0; p < 2; ++p) {
            const int t = (tid >> 3) + p * 32;
            const size_t rowb = ((size_t)b * 2048 + t0 + t) * 1056;
            *(short8*)&xp[rowb + kloc]       = *(const short8*)&tr_[t][dc * 8];
            *(short8*)&xp[rowb + 528 + kloc] = *(const short8*)&ti_[t][dc * 8];
        }
    }
}

// ---------- transpose planes (b,512,T) -> k-major (b,T,512) bf16 ----------
template<int SRC32>
__global__ __launch_bounds__(256) void tr_k(const void* __restrict__ src,
                                            unsigned short* __restrict__ dst)
{
    const int t0 = blockIdx.x * 64, k0 = blockIdx.y * 64, b = blockIdx.z;
    __shared__ unsigned short tile[64][72];
    const int tid = threadIdx.x;
    if (SRC32) {
        const float* sf = (const float*)src;
        const int tp = tid & 31, kl0 = tid >> 5;
#pragma unroll
        for (int p = 0; p < 8; ++p) {
            const int kl = kl0 + p * 8;
            const float2 v = *(const float2*)(sf + ((size_t)b * 512 + k0 + kl) * 2048 + t0 + tp * 2);
            tile[tp * 2 + 0][kl] = f2bf(v.x);
            tile[tp * 2 + 1][kl] = f2bf(v.y);
        }
    } else {
        const unsigned short* su = (const unsigned short*)src;
        const int toct = tid & 7, kl0 = tid >> 3;
#pragma unroll
        for (int p = 0; p < 2; ++p) {
            const int kl = kl0 + p * 32;
            const short8 v = *(const short8*)(su + ((size_t)b * 512 + k0 + kl) * 2048 + t0 + toct * 8);
#pragma unroll
            for (int j = 0; j < 8; ++j) tile[toct * 8 + j][kl] = ((const unsigned short*)&v)[j];
        }
    }
    __syncthreads();
    const int dc = tid & 7;
#pragma unroll
    for (int p = 0; p < 2; ++p) {
        const int t = (tid >> 3) + p * 32;
        *(short8*)&dst[((size_t)b * 2048 + t0 + t) * 512 + k0 + dc * 8] = *(const short8*)&tile[t][dc * 8];
    }
}

// ---------- bf16 MFMA GEMM: out(b,M,T) = A(Mp x Kp) * Bm(b,T,Kp)^T + bias ----------
template<int MODE>
__global__ __launch_bounds__(256, 2) void mgemm_k(
    const unsigned short* __restrict__ A, const float* __restrict__ bias,
    const unsigned short* __restrict__ Bm, float* __restrict__ out,
    int M, int Kp)
{
    __shared__ unsigned short As[4096];  // [m 0..127][k 0..31]
    __shared__ unsigned short Bs[4096];  // [t 0..127][k 0..31]
    const int tid = threadIdx.x;
    const int w = tid >> 6, lane = tid & 63;
    const int m0 = blockIdx.x * 128, t0 = blockIdx.y * 128, b = blockIdx.z;
    const int wm = w & 1, wn = w >> 1;

    const unsigned short* Ab = A + (size_t)m0 * Kp;
    const unsigned short* Bb = Bm + ((size_t)b * 2048 + t0) * Kp;

    const int c0 = w * 64 + lane;
    const int r0 = c0 >> 2, q0 = (c0 & 3) * 8;
    const int c1 = c0 + 256;
    const int r1 = c1 >> 2, q1 = (c1 & 3) * 8;
    unsigned short* As0 = &As[(size_t)(w * 64) * 8];
    unsigned short* As1 = &As[(size_t)(w * 64 + 256) * 8];
    unsigned short* Bs0 = &Bs[(size_t)(w * 64) * 8];
    unsigned short* Bs1 = &Bs[(size_t)(w * 64 + 256) * 8];

    float4v acc[4][4];
#pragma unroll
    for (int i = 0; i < 4; ++i)
#pragma unroll
        for (int j = 0; j < 4; ++j) acc[i][j] = (float4v){0.f, 0.f, 0.f, 0.f};

    const int arow = wm * 64 + (lane & 15);
    const int brow = wn * 64 + (lane & 15);
    const int kq = (lane >> 4) * 8;

    for (int k0 = 0; k0 < Kp; k0 += 32) {
        ASYNC_COPY16(Ab + (size_t)r0 * Kp + k0 + q0, As0);
        ASYNC_COPY16(Ab + (size_t)r1 * Kp + k0 + q1, As1);
        ASYNC_COPY16(Bb + (size_t)r0 * Kp + k0 + q0, Bs0);
        ASYNC_COPY16(Bb + (size_t)r1 * Kp + k0 + q1, Bs1);
        __syncthreads();
        short8 af[4], bf[4];
#pragma unroll
        for (int i = 0; i < 4; ++i) af[i] = *(const short8*)&As[(arow + i * 16) * 32 + kq];
#pragma unroll
        for (int j = 0; j < 4; ++j) bf[j] = *(const short8*)&Bs[(brow + j * 16) * 32 + kq];
#pragma unroll
        for (int i = 0; i < 4; ++i)
#pragma unroll
            for (int j = 0; j < 4; ++j)
                acc[i][j] = __builtin_amdgcn_mfma_f32_16x16x32_bf16(af[i], bf[j], acc[i][j], 0, 0, 0);
        __syncthreads();
    }

    const int col = lane & 15;
    const int rq = (lane >> 4) * 4;
#pragma unroll
    for (int i = 0; i < 4; ++i) {
        const int mloc = wm * 64 + i * 16 + rq;
#pragma unroll
        for (int r = 0; r < 4; ++r) {
            const int m = m0 + mloc + r;
            if (MODE == 1 && m >= M) continue;
            const float bs = bias[m];
#pragma unroll
            for (int j = 0; j < 4; ++j) {
                const int t = t0 + wn * 64 + j * 16 + col;
                const float vv = acc[i][j][r] + bs;
                if (MODE == 0) {
                    out[((size_t)b * 512 + m) * 2048 + t] = vv;
                } else {
                    const int comp = m >= 514;
                    const int g = m - 514 * comp;
                    out[(((size_t)b * 514 + g) * 2048 + t) * 2 + comp] = vv;
                }
            }
        }
    }
}

// ---------- S4D diagonal SSM scan + D-skip + gelu -> bf16 planes ----------
// Block = 256 threads (4 waves) per (b,h). Wave wv = {half, mg}: half = wv>>1
// picks the time half (1024 steps), mg = wv&1 picks a mode group of 16.
// Lane owns 16 timesteps. Per-thread working set = ur/ui/yr/yi[16] = 64 floats
// (+~40 transients), which fits in arch VGPRs. The previous 32-t/lane layout
// needed a 128-float working set that the allocator kept in AGPRs
// (VGPR_Count=80) and ~2.4x-inflated the VALU stream with v_accvgpr moves
// (R0 counters: 83% VALUBusy * 81us vs ~30us of useful FMA issue).
// Cross-half scan carry goes through LDS once per mode: half 0 publishes its
// t=1024 state, half 1 adds carry * f^lane (f = w^16) to its local exclusive
// prefix before pass 2.
__global__ __launch_bounds__(256, 3) void s4scan_k(
    const float* __restrict__ z, unsigned short* __restrict__ y,
    const float* __restrict__ log_dt, const float* __restrict__ log_A_real,
    const float* __restrict__ A_imag, const float* __restrict__ C_r,
    const float* __restrict__ C_i, const float* __restrict__ Dsk, int l)
{
    const int h = blockIdx.x, b = blockIdx.y;
    const int tid = threadIdx.x;
    const int wv = tid >> 6, lane = tid & 63;
    const int half = wv >> 1, mg = wv & 1;
    __shared__ float2 wsh[32], csh[32];
    __shared__ float dsh;
    __shared__ float2 carry[2][16];
    __shared__ float buf[2][128][18];

    if (tid < 32) {
        const size_t pidx = ((size_t)l * 256 + h) * 32 + tid;
        const float dt = __expf(log_dt[l * 256 + h]);
        const float Ar = -__expf(log_A_real[pidx]);
        const float Ai = A_imag[pidx];
        const float er = __expf(Ar * dt);
        float sv, cv;
        __sincosf(Ai * dt, &sv, &cv);
        const float wr = er * cv, wi = er * sv;
        const float den = 1.f / (Ar * Ar + Ai * Ai);
        const float nr = wr - 1.f, ni = wi;
        const float qr = (nr * Ar + ni * Ai) * den;
        const float qi = (ni * Ar - nr * Ai) * den;
        const float cr = C_r[pidx], ci = C_i[pidx];
        wsh[tid] = make_float2(wr, wi);
        csh[tid] = make_float2(cr * qr - ci * qi, cr * qi + ci * qr);
    }
    if (tid == 32) dsh = Dsk[l * 256 + h];
    __syncthreads();

    // lane owns t in [half*1024 + lane*16, +16)
    const float* zrp = z + ((size_t)b * 512 + h) * 2048 + half * 1024 + lane * 16;
    const float* zip = zrp + 256 * 2048;
    float ur[16], ui[16], yr[16], yi[16];
#pragma unroll
    for (int j = 0; j < 4; ++j) {
        *(float4*)&ur[j * 4] = *(const float4*)(zrp + j * 4);
        *(float4*)&ui[j * 4] = *(const float4*)(zip + j * 4);
    }
    // D-skip folded into the mg==0 partial of each half (linear term)
    if (mg == 0) {
        const float dv = dsh;
#pragma unroll
        for (int t = 0; t < 16; ++t) { yr[t] = dv * ur[t]; yi[t] = dv * ui[t]; }
    } else {
#pragma unroll
        for (int t = 0; t < 16; ++t) { yr[t] = 0.f; yi[t] = 0.f; }
    }

#pragma unroll 1
    for (int n = 0; n < 16; ++n) {
        const float2 wm = wsh[mg * 16 + n], ct = csh[mg * 16 + n];
        // pass 1: chunk-local final state (zero init)
        float xr = 0.f, xi = 0.f;
#pragma unroll
        for (int t = 0; t < 16; ++t) {
            const float nxr = __builtin_fmaf(wm.x, xr, __builtin_fmaf(-wm.y, xi, ur[t]));
            const float nxi = __builtin_fmaf(wm.x, xi, __builtin_fmaf(wm.y, xr, ui[t]));
            xr = nxr; xi = nxi;
        }
        // f = w^16
        float fr = wm.x, fi = wm.y;
#pragma unroll
        for (int s = 0; s < 4; ++s) { const float a2 = fr * fr - fi * fi, b2 = 2.f * fr * fi; fr = a2; fi = b2; }
        // inclusive wave prefix over chunk-final states with multiplier f
        float qrv = xr, qiv = xi, pr = fr, pi = fi;
#pragma unroll
        for (int s = 0; s < 6; ++s) {
            const int d = 1 << s;
            const float sr = __shfl_up(qrv, (unsigned)d);
            const float si = __shfl_up(qiv, (unsigned)d);
            if (lane >= d) {
                qrv += pr * sr - pi * si;
                qiv += pr * si + pi * sr;
            }
            const float a2 = pr * pr - pi * pi, b2 = 2.f * pr * pi;
            pr = a2; pi = b2;
        }
        float vr = __shfl_up(qrv, 1u);
        float vi = __shfl_up(qiv, 1u);
        if (lane == 0) { vr = 0.f; vi = 0.f; }
        // cross-half carry: half 0 publishes its t=1024 state (lane 63
        // inclusive prefix); half 1 builds g = f^lane by conditional
        // squaring-product, then applies carry*g after the sync.
        float gr = 1.f, gi = 0.f;
        if (half == 0) {
            if (lane == 63) carry[mg][n] = make_float2(qrv, qiv);
        } else {
            float p2r = fr, p2i = fi;
#pragma unroll
            for (int s = 0; s < 6; ++s) {
                if ((lane >> s) & 1) {
                    const float tr2 = gr * p2r - gi * p2i;
                    gi = gr * p2i + gi * p2r;
                    gr = tr2;
                }
                const float a2 = p2r * p2r - p2i * p2i, b2 = 2.f * p2r * p2i;
                p2r = a2; p2i = b2;
            }
        }
        __syncthreads();
        if (half) {
            const float2 cv = carry[mg][n];
            vr += cv.x * gr - cv.y * gi;
            vi += cv.x * gi + cv.y * gr;
        }
        // pass 2: carry-init scan + output accumulation
        float sr2 = vr, si2 = vi;
#pragma unroll
        for (int t = 0; t < 16; ++t) {
            const float nsr = __builtin_fmaf(wm.x, sr2, __builtin_fmaf(-wm.y, si2, ur[t]));
            const float nsi = __builtin_fmaf(wm.x, si2, __builtin_fmaf(wm.y, sr2, ui[t]));
            sr2 = nsr; si2 = nsi;
            yr[t] = __builtin_fmaf(ct.x, sr2, __builtin_fmaf(-ct.y, si2, yr[t]));
            yi[t] = __builtin_fmaf(ct.x, si2, __builtin_fmaf(ct.y, sr2, yi[t]));
        }
    }

    // 2-phase LDS reduction over the two mode groups (row stride 18 floats:
    // lanes 16 apart alias banks 4-way on the float2 ops -> ~1.6x on these
    // few LDS ops only, negligible).
    const int cc = half * 64 + lane;  // chunk index over t: t = 16*cc + k
    if (mg == 0) {
#pragma unroll
        for (int j = 0; j < 8; ++j) {
            *(float2*)&buf[0][cc][j * 2] = make_float2(yr[j * 2], yr[j * 2 + 1]);
            *(float2*)&buf[1][cc][j * 2] = make_float2(yi[j * 2], yi[j * 2 + 1]);
        }
    }
    __syncthreads();
    if (mg == 1) {
#pragma unroll
        for (int j = 0; j < 8; ++j) {
            float2 a = *(const float2*)&buf[0][cc][j * 2];
            a.x += yr[j * 2]; a.y += yr[j * 2 + 1];
            *(float2*)&buf[0][cc][j * 2] = a;
            float2 bq = *(const float2*)&buf[1][cc][j * 2];
            bq.x += yi[j * 2]; bq.y += yi[j * 2 + 1];
            *(float2*)&buf[1][cc][j * 2] = bq;
        }
    }
    __syncthreads();

    // final: gelu + bf16 pack + coalesced stores. Thread tid owns t = tid*8..+8.
    const int row = tid >> 1, pos = (tid & 1) * 8;
    unsigned short* yrp = y + ((size_t)b * 512 + h) * 2048 + tid * 8;
    unsigned short* yip = yrp + 256 * 2048;
    {
        short8 vr8, vi8;
#pragma unroll
        for (int j = 0; j < 8; ++j) {
            ((unsigned short*)&vr8)[j] = f2bf(gelu_tanh(buf[0][row][pos + j]));
            ((unsigned short*)&vi8)[j] = f2bf(gelu_tanh(buf[1][row][pos + j]));
        }
        *(short8*)yrp = vr8;
        *(short8*)yip = vi8;
    }
}

// ---------- residual + channel LayerNorm (fp32 planes) ----------
__global__ __launch_bounds__(256) void ln_k(
    const float* __restrict__ o, float* __restrict__ z,
    const float* __restrict__ gamr, const float* __restrict__ gami,
    const float* __restrict__ betr, const float* __restrict__ beti, int l)
{
    const int tt = blockIdx.x, b = blockIdx.y, comp = blockIdx.z;
    const int tid = threadIdx.x;
    const int tloc = tid & 31, gq = tid >> 5;
    __shared__ float tile[256][33];
    __shared__ float red[2][8][32];
    __shared__ float stat[2][32];
    const int t0 = tt * 32;
    const size_t base = ((size_t)b * 512 + comp * 256) * 2048 + t0 + tloc;

#pragma unroll 4
    for (int j = 0; j < 32; ++j) {
        const int g = j * 8 + gq;
        const size_t idx = base + (size_t)g * 2048;
        tile[g][tloc] = o[idx] + z[idx];
    }
    __syncthreads();
    float s = 0.f, sq = 0.f;
#pragma unroll 4
    for (int g2 = 0; g2 < 32; ++g2) {
        const float v = tile[gq * 32 + g2][tloc];
        s += v; sq += v * v;
    }
    red[0][gq][tloc] = s; red[1][gq][tloc] = sq;
    __syncthreads();
    if (tid < 32) {
        float S = 0.f, SQ = 0.f;
#pragma unroll
        for (int q = 0; q < 8; ++q) { S += red[0][q][tid]; SQ += red[1][q][tid]; }
        const float m = S * (1.f / 256.f);
        const float var = SQ * (1.f / 256.f) - m * m;
        stat[0][tid] = m;
        stat[1][tid] = rsqrtf(var + 1e-5f);
    }
    __syncthreads();
    const float* gam = (comp ? gami : gamr) + l * 256;
    const float* bet = (comp ? beti : betr) + l * 256;
    const float m = stat[0][tloc], rs = stat[1][tloc];
#pragma unroll 4
    for (int j = 0; j < 32; ++j) {
        const int g = j * 8 + gq;
        z[base + (size_t)g * 2048] = (tile[g][tloc] - m) * rs * gam[g] + bet[g];
    }
}

extern "C" void kernel_launch(void* const* d_in, const int* in_sizes, int n_in,
                              void* d_out, int out_size, void* d_ws, size_t ws_size,
                              hipStream_t stream)
{
    const float* x        = (const float*)d_in[0];
    const float* enc_Wr   = (const float*)d_in[1];
    const float* enc_Wi   = (const float*)d_in[2];
    const float* enc_br   = (const float*)d_in[3];
    const float* enc_bi   = (const float*)d_in[4];
    const float* log_dt   = (const float*)d_in[5];
    const float* log_A_r  = (const float*)d_in[6];
    const float* A_imag   = (const float*)d_in[7];
    const float* C_r      = (const float*)d_in[8];
    const float* C_i      = (const float*)d_in[9];
    const float* Dp       = (const float*)d_in[10];
    const float* out_Wr   = (const float*)d_in[11];
    const float* out_Wi   = (const float*)d_in[12];
    const float* out_br   = (const float*)d_in[13];
    const float* out_bi   = (const float*)d_in[14];
    const float* ln_gr    = (const float*)d_in[15];
    const float* ln_gi    = (const float*)d_in[16];
    const float* ln_br    = (const float*)d_in[17];
    const float* ln_bi    = (const float*)d_in[18];
    const float* dec_Wr   = (const float*)d_in[19];
    const float* dec_Wi   = (const float*)d_in[20];
    const float* dec_br   = (const float*)d_in[21];
    const float* dec_bi   = (const float*)d_in[22];

    // ---- workspace layout (bytes) ----
    uint8_t* W = (uint8_t*)d_ws;
    float* z             = (float*)W;                       // 33,554,432
    unsigned short* zp   = (unsigned short*)(W + 33554432); // 16,777,216
    unsigned short* A_enc= (unsigned short*)(W + 50331648); // 512x1056x2  = 1,081,344
    unsigned short* A_lay= (unsigned short*)(W + 51412992); // 4x512x512x2 = 2,097,152
    unsigned short* A_dec= (unsigned short*)(W + 53510144); // 1152x512x2  = 1,179,648
    float* b_enc         = (float*)(W + 54689792);          // 512 f
    float* b_lay         = (float*)(W + 54691840);          // 2048 f
    float* b_dec         = (float*)(W + 54700032);          // 1028 f

    // ---- d_out doubles as scratch (67.37 MB total) ----
    float* o            = (float*)d_out;                                   // 33,554,432
    unsigned short* y   = (unsigned short*)((uint8_t*)d_out + 33554432);   // 16,777,216
    unsigned short* yp  = (unsigned short*)((uint8_t*)d_out + 50331648);   // 16,777,216
    unsigned short* xp  = (unsigned short*)d_out;  // 34,603,008; dead after encoder GEMM

    // ---- build weights/biases ----
    buildw_k<<<2112, 256, 0, stream>>>(enc_Wr, enc_Wi, A_enc, 256, 514, 528, 1056, 512);
    for (int l = 0; l < 4; ++l)
        buildw_k<<<1024, 256, 0, stream>>>(out_Wr + (size_t)l * 65536, out_Wi + (size_t)l * 65536,
                                           A_lay + (size_t)l * 262144, 256, 256, 256, 512, 512);
    buildw_k<<<2304, 256, 0, stream>>>(dec_Wr, dec_Wi, A_dec, 514, 256, 256, 512, 1152);
    build_bias_k<<<2, 256, 0, stream>>>(enc_br, enc_bi, b_enc, 256);
    for (int l = 0; l < 4; ++l)
        build_bias_k<<<2, 256, 0, stream>>>(out_br + l * 256, out_bi + l * 256, b_lay + l * 512, 256);
    build_bias_k<<<5, 256, 0, stream>>>(dec_br, dec_bi, b_dec, 514);

    // ---- encoder: pack x -> xp, GEMM -> z ----
    packx_k<<<dim3(32, 9, 8), 256, 0, stream>>>(x, xp);
    mgemm_k<0><<<dim3(4, 16, 8), 256, 0, stream>>>(A_enc, b_enc, xp, z, 512, 1056);

    // ---- layers ----
    for (int l = 0; l < 4; ++l) {
        s4scan_k<<<dim3(256, 8), 256, 0, stream>>>(z, y, log_dt, log_A_r, A_imag, C_r, C_i, Dp, l);
        tr_k<0><<<dim3(32, 8, 8), 256, 0, stream>>>(y, yp);
        mgemm_k<0><<<dim3(4, 16, 8), 256, 0, stream>>>(A_lay + (size_t)l * 262144,
                                                       b_lay + l * 512, yp, o, 512, 512);
        ln_k<<<dim3(64, 8, 2), 256, 0, stream>>>(o, z, ln_gr, ln_gi, ln_br, ln_bi, l);
    }

    // ---- decoder: z -> zp, GEMM -> d_out interleaved (overwrites all scratch) ----
    tr_k<1><<<dim3(32, 8, 8), 256, 0, stream>>>(z, zp);
    mgemm_k<1><<<dim3(9, 16, 8), 256, 0, stream>>>(A_dec, b_dec, zp, (float*)d_out, 1028, 512);
}

// Round 2
// 733.301 us; speedup vs baseline: 1.0107x; 1.0107x over previous
//
#include <hip/hip_runtime.h>
#include <cstddef>
#include <cstdint>

// B=8, C=2, Hf=257, T=2048, D_IN=514, DM=256, NL=4, N=32
// Activations: fp32 planes (b, 2*DM=512, T). GEMMs run bf16 MFMA with
// k-major bf16 activation copies (b, T, Kp).

typedef __attribute__((ext_vector_type(8))) short short8;
typedef __attribute__((ext_vector_type(4))) float float4v;

__device__ __forceinline__ unsigned short f2bf(float f) {
    union { float f; unsigned u; } v; v.f = f;
    const unsigned r = v.u + 0x7fffu + ((v.u >> 16) & 1u);  // RNE
    return (unsigned short)(r >> 16);
}

__device__ __forceinline__ float gelu_tanh(float x) {
    const float x3 = x * x * x;
    const float v  = 0.7978845608028654f * (x + 0.044715f * x3);
    const float e  = __expf(2.f * v);
    const float th = 1.f - 2.f / (e + 1.f);
    return 0.5f * x * (1.f + th);
}

#define ASYNC_COPY16(gp, lp) __builtin_amdgcn_global_load_lds( \
    (const __attribute__((address_space(1))) unsigned int*)(gp), \
    (__attribute__((address_space(3))) unsigned int*)(lp), 16, 0, 0)

// ---------- builders: bf16 real-rep of complex weights, padded ----------
__global__ __launch_bounds__(256) void buildw_k(
    const float* __restrict__ Wr, const float* __restrict__ Wi,
    unsigned short* __restrict__ A, int G, int H, int Hoff, int Kp, int Mp)
{
    const long long i = (long long)blockIdx.x * 256 + threadIdx.x;
    if (i >= (long long)Mp * Kp) return;
    const int m = (int)(i / Kp), k = (int)(i % Kp);
    float val = 0.f;
    if (m < 2 * G) {
        const int ri = m >= G;
        const int g = m - ri * G;
        const int blk = k >= Hoff;
        const int hh = k - blk * Hoff;
        if (hh < H) {
            const float wr = Wr[(size_t)g * H + hh];
            const float wi = Wi[(size_t)g * H + hh];
            val = ri ? (blk ? wr : wi) : (blk ? -wi : wr);
        }
    }
    A[i] = f2bf(val);
}

__global__ __launch_bounds__(256) void build_bias_k(
    const float* __restrict__ br, const float* __restrict__ bi,
    float* __restrict__ bias, int G)
{
    const int i = blockIdx.x * 256 + threadIdx.x;
    if (i < G) bias[i] = br[i];
    else if (i < 2 * G) bias[i] = bi[i - G];
}

// ---------- encoder input pack: x (b,514,T,2) fp32 -> xp (b,T,1056) bf16 ----------
__global__ __launch_bounds__(256) void packx_k(const float* __restrict__ x,
                                               unsigned short* __restrict__ xp)
{
    const int t0 = blockIdx.x * 64, d0 = blockIdx.y * 64, b = blockIdx.z;
    __shared__ unsigned short tr_[64][72];
    __shared__ unsigned short ti_[64][72];
    const int tid = threadIdx.x;
    const int tp = tid & 31, dl0 = tid >> 5;
#pragma unroll
    for (int p = 0; p < 8; ++p) {
        const int d = dl0 + p * 8;
        const int gd = d0 + d;
        float4 v = make_float4(0.f, 0.f, 0.f, 0.f);
        if (gd < 514) v = *(const float4*)(x + (((size_t)b * 514 + gd) * 2048 + t0 + tp * 2) * 2);
        tr_[tp * 2 + 0][d] = f2bf(v.x); ti_[tp * 2 + 0][d] = f2bf(v.y);
        tr_[tp * 2 + 1][d] = f2bf(v.z); ti_[tp * 2 + 1][d] = f2bf(v.w);
    }
    __syncthreads();
    const int dc = tid & 7;
    const int kloc = d0 + dc * 8;
    if (kloc < 528) {
#pragma unroll
        for (int p = 0; p < 2; ++p) {
            const int t = (tid >> 3) + p * 32;
            const size_t rowb = ((size_t)b * 2048 + t0 + t) * 1056;
            *(short8*)&xp[rowb + kloc]       = *(const short8*)&tr_[t][dc * 8];
            *(short8*)&xp[rowb + 528 + kloc] = *(const short8*)&ti_[t][dc * 8];
        }
    }
}

// ---------- transpose planes (b,512,T) -> k-major (b,T,512) bf16 ----------
template<int SRC32>
__global__ __launch_bounds__(256) void tr_k(const void* __restrict__ src,
                                            unsigned short* __restrict__ dst)
{
    const int t0 = blockIdx.x * 64, k0 = blockIdx.y * 64, b = blockIdx.z;
    __shared__ unsigned short tile[64][72];
    const int tid = threadIdx.x;
    if (SRC32) {
        const float* sf = (const float*)src;
        const int tp = tid & 31, kl0 = tid >> 5;
#pragma unroll
        for (int p = 0; p < 8; ++p) {
            const int kl = kl0 + p * 8;
            const float2 v = *(const float2*)(sf + ((size_t)b * 512 + k0 + kl) * 2048 + t0 + tp * 2);
            tile[tp * 2 + 0][kl] = f2bf(v.x);
            tile[tp * 2 + 1][kl] = f2bf(v.y);
        }
    } else {
        const unsigned short* su = (const unsigned short*)src;
        const int toct = tid & 7, kl0 = tid >> 3;
#pragma unroll
        for (int p = 0; p < 2; ++p) {
            const int kl = kl0 + p * 32;
            const short8 v = *(const short8*)(su + ((size_t)b * 512 + k0 + kl) * 2048 + t0 + toct * 8);
#pragma unroll
            for (int j = 0; j < 8; ++j) tile[toct * 8 + j][kl] = ((const unsigned short*)&v)[j];
        }
    }
    __syncthreads();
    const int dc = tid & 7;
#pragma unroll
    for (int p = 0; p < 2; ++p) {
        const int t = (tid >> 3) + p * 32;
        *(short8*)&dst[((size_t)b * 2048 + t0 + t) * 512 + k0 + dc * 8] = *(const short8*)&tile[t][dc * 8];
    }
}

// ---------- bf16 MFMA GEMM: out(b,M,T) = A(Mp x Kp) * Bm(b,T,Kp)^T + bias ----------
template<int MODE>
__global__ __launch_bounds__(256, 2) void mgemm_k(
    const unsigned short* __restrict__ A, const float* __restrict__ bias,
    const unsigned short* __restrict__ Bm, float* __restrict__ out,
    int M, int Kp)
{
    __shared__ unsigned short As[4096];  // [m 0..127][k 0..31]
    __shared__ unsigned short Bs[4096];  // [t 0..127][k 0..31]
    const int tid = threadIdx.x;
    const int w = tid >> 6, lane = tid & 63;
    const int m0 = blockIdx.x * 128, t0 = blockIdx.y * 128, b = blockIdx.z;
    const int wm = w & 1, wn = w >> 1;

    const unsigned short* Ab = A + (size_t)m0 * Kp;
    const unsigned short* Bb = Bm + ((size_t)b * 2048 + t0) * Kp;

    const int c0 = w * 64 + lane;
    const int r0 = c0 >> 2, q0 = (c0 & 3) * 8;
    const int c1 = c0 + 256;
    const int r1 = c1 >> 2, q1 = (c1 & 3) * 8;
    unsigned short* As0 = &As[(size_t)(w * 64) * 8];
    unsigned short* As1 = &As[(size_t)(w * 64 + 256) * 8];
    unsigned short* Bs0 = &Bs[(size_t)(w * 64) * 8];
    unsigned short* Bs1 = &Bs[(size_t)(w * 64 + 256) * 8];

    float4v acc[4][4];
#pragma unroll
    for (int i = 0; i < 4; ++i)
#pragma unroll
        for (int j = 0; j < 4; ++j) acc[i][j] = (float4v){0.f, 0.f, 0.f, 0.f};

    const int arow = wm * 64 + (lane & 15);
    const int brow = wn * 64 + (lane & 15);
    const int kq = (lane >> 4) * 8;

    for (int k0 = 0; k0 < Kp; k0 += 32) {
        ASYNC_COPY16(Ab + (size_t)r0 * Kp + k0 + q0, As0);
        ASYNC_COPY16(Ab + (size_t)r1 * Kp + k0 + q1, As1);
        ASYNC_COPY16(Bb + (size_t)r0 * Kp + k0 + q0, Bs0);
        ASYNC_COPY16(Bb + (size_t)r1 * Kp + k0 + q1, Bs1);
        __syncthreads();
        short8 af[4], bf[4];
#pragma unroll
        for (int i = 0; i < 4; ++i) af[i] = *(const short8*)&As[(arow + i * 16) * 32 + kq];
#pragma unroll
        for (int j = 0; j < 4; ++j) bf[j] = *(const short8*)&Bs[(brow + j * 16) * 32 + kq];
#pragma unroll
        for (int i = 0; i < 4; ++i)
#pragma unroll
            for (int j = 0; j < 4; ++j)
                acc[i][j] = __builtin_amdgcn_mfma_f32_16x16x32_bf16(af[i], bf[j], acc[i][j], 0, 0, 0);
        __syncthreads();
    }

    const int col = lane & 15;
    const int rq = (lane >> 4) * 4;
#pragma unroll
    for (int i = 0; i < 4; ++i) {
        const int mloc = wm * 64 + i * 16 + rq;
#pragma unroll
        for (int r = 0; r < 4; ++r) {
            const int m = m0 + mloc + r;
            if (MODE == 1 && m >= M) continue;
            const float bs = bias[m];
#pragma unroll
            for (int j = 0; j < 4; ++j) {
                const int t = t0 + wn * 64 + j * 16 + col;
                const float vv = acc[i][j][r] + bs;
                if (MODE == 0) {
                    out[((size_t)b * 512 + m) * 2048 + t] = vv;
                } else {
                    const int comp = m >= 514;
                    const int g = m - 514 * comp;
                    out[(((size_t)b * 514 + g) * 2048 + t) * 2 + comp] = vv;
                }
            }
        }
    }
}

// ---------- S4D diagonal SSM scan + D-skip + gelu -> bf16 planes ----------
// LDS-resident design (R2). The R0/R1 designs kept 128/64-float per-thread
// arrays; the allocator caps arch VGPRs at ~72-80 here regardless of
// __launch_bounds__, shuffles those arrays through AGPRs, and ~2.3x-inflates
// the VALU stream (measured both rounds: VALU-issue ~67us vs ~28us useful).
// R2 keeps u and y in LDS and caps the live per-thread state at ~24 floats:
//   stage:   u (zr,zi) -> us[64][33] float2 (2-way bank alias = free)
//   sweep1:  wave wv owns modes 8wv..8wv+7, lane = 32-t chunk. 8 complex
//            states in regs (16f), u streamed from LDS (1 ds_read_b64/t,
//            amortized over 8 modes). Per-mode 64-lane butterfly ->
//            exclusive chunk-start states vsh[32][64].
//   sweep2:  thread = (chunk c=tid>>2, mode-quarter q=tid&3), two 4-mode
//            passes (live: 4 states + 4 w + 4 c = 24f). Per-t partial is
//            reduced over the 4 adjacent lanes via 2x shfl_xor; lane q==0
//            RMWs ys[64][33]. No atomics; chunk c has a unique owner wave.
//   final:   y = ys + D*us, gelu, bf16 pack, coalesced stores.
// 3 __syncthreads total. LDS ~50.7 KB -> 3 blocks/CU.
__global__ __launch_bounds__(256) void s4scan_k(
    const float* __restrict__ z, unsigned short* __restrict__ y,
    const float* __restrict__ log_dt, const float* __restrict__ log_A_real,
    const float* __restrict__ A_imag, const float* __restrict__ C_r,
    const float* __restrict__ C_i, const float* __restrict__ Dsk, int l)
{
    const int h = blockIdx.x, b = blockIdx.y;
    const int tid = threadIdx.x;
    const int lane = tid & 63, wv = tid >> 6;
    __shared__ float2 wsh[32], csh[32];
    __shared__ float dsh;
    __shared__ float2 us[64][33];
    __shared__ float2 ys[64][33];
    __shared__ float2 vsh[32][64];

    if (tid < 32) {
        const size_t pidx = ((size_t)l * 256 + h) * 32 + tid;
        const float dt = __expf(log_dt[l * 256 + h]);
        const float Ar = -__expf(log_A_real[pidx]);
        const float Ai = A_imag[pidx];
        const float er = __expf(Ar * dt);
        float sv, cv;
        __sincosf(Ai * dt, &sv, &cv);
        const float wr = er * cv, wi = er * sv;
        const float den = 1.f / (Ar * Ar + Ai * Ai);
        const float nr = wr - 1.f, ni = wi;
        const float qr = (nr * Ar + ni * Ai) * den;
        const float qi = (ni * Ar - nr * Ai) * den;
        const float cr = C_r[pidx], ci = C_i[pidx];
        wsh[tid] = make_float2(wr, wi);
        csh[tid] = make_float2(cr * qr - ci * qi, cr * qi + ci * qr);
    }
    if (tid == 32) dsh = Dsk[l * 256 + h];

    // ---- stage u into LDS + zero ys. Thread tid owns t = tid*8..+8. ----
    const int c0q = tid >> 2, t0q = (tid & 3) * 8;
    {
        const float* zrp = z + ((size_t)b * 512 + h) * 2048 + tid * 8;
        const float* zip = zrp + 256 * 2048;
        const float4 r0 = *(const float4*)zrp, r1 = *(const float4*)(zrp + 4);
        const float4 i0 = *(const float4*)zip, i1 = *(const float4*)(zip + 4);
        float2* up = &us[c0q][t0q];
        up[0] = make_float2(r0.x, i0.x); up[1] = make_float2(r0.y, i0.y);
        up[2] = make_float2(r0.z, i0.z); up[3] = make_float2(r0.w, i0.w);
        up[4] = make_float2(r1.x, i1.x); up[5] = make_float2(r1.y, i1.y);
        up[6] = make_float2(r1.z, i1.z); up[7] = make_float2(r1.w, i1.w);
        float2* yp0 = &ys[c0q][t0q];
#pragma unroll
        for (int j = 0; j < 8; ++j) yp0[j] = make_float2(0.f, 0.f);
    }
    __syncthreads();

    // ---- sweep 1: chunk-local finals + butterfly -> exclusive states ----
    {
        float2 w8[8], x8[8];
#pragma unroll
        for (int j = 0; j < 8; ++j) {
            w8[j] = wsh[wv * 8 + j];
            x8[j] = make_float2(0.f, 0.f);
        }
#pragma unroll 8
        for (int tt = 0; tt < 32; ++tt) {
            const float2 u = us[lane][tt];
#pragma unroll
            for (int j = 0; j < 8; ++j) {
                const float nxr = __builtin_fmaf(w8[j].x, x8[j].x, __builtin_fmaf(-w8[j].y, x8[j].y, u.x));
                const float nxi = __builtin_fmaf(w8[j].x, x8[j].y, __builtin_fmaf(w8[j].y, x8[j].x, u.y));
                x8[j].x = nxr; x8[j].y = nxi;
            }
        }
#pragma unroll
        for (int j = 0; j < 8; ++j) {
            // f = w^32
            float fr = w8[j].x, fi = w8[j].y;
#pragma unroll
            for (int s = 0; s < 5; ++s) { const float a2 = fr * fr - fi * fi, b2 = 2.f * fr * fi; fr = a2; fi = b2; }
            // inclusive wave prefix over chunk-final states with multiplier f
            float qrv = x8[j].x, qiv = x8[j].y, pr = fr, pi = fi;
#pragma unroll
            for (int s = 0; s < 6; ++s) {
                const int d = 1 << s;
                const float sr = __shfl_up(qrv, (unsigned)d);
                const float si = __shfl_up(qiv, (unsigned)d);
                if (lane >= d) {
                    qrv += pr * sr - pi * si;
                    qiv += pr * si + pi * sr;
                }
                const float a2 = pr * pr - pi * pi, b2 = 2.f * pr * pi;
                pr = a2; pi = b2;
            }
            float vr = __shfl_up(qrv, 1u);
            float vi = __shfl_up(qiv, 1u);
            if (lane == 0) { vr = 0.f; vi = 0.f; }
            vsh[wv * 8 + j][lane] = make_float2(vr, vi);
        }
    }
    __syncthreads();

    // ---- sweep 2: carry-init scan + output accumulation into ys ----
    {
        const int q = tid & 3;
#pragma unroll
        for (int g = 0; g < 2; ++g) {
            const int nb = q * 8 + g * 4;
            float2 w4[4], cc4[4], s4[4];
#pragma unroll
            for (int j = 0; j < 4; ++j) {
                w4[j] = wsh[nb + j];
                cc4[j] = csh[nb + j];
                s4[j] = vsh[nb + j][c0q];
            }
#pragma unroll 8
            for (int tt = 0; tt < 32; ++tt) {
                const float2 u = us[c0q][tt];
                float pyr = 0.f, pyi = 0.f;
#pragma unroll
                for (int j = 0; j < 4; ++j) {
                    const float nsr = __builtin_fmaf(w4[j].x, s4[j].x, __builtin_fmaf(-w4[j].y, s4[j].y, u.x));
                    const float nsi = __builtin_fmaf(w4[j].x, s4[j].y, __builtin_fmaf(w4[j].y, s4[j].x, u.y));
                    s4[j].x = nsr; s4[j].y = nsi;
                    pyr = __builtin_fmaf(cc4[j].x, nsr, __builtin_fmaf(-cc4[j].y, nsi, pyr));
                    pyi = __builtin_fmaf(cc4[j].x, nsi, __builtin_fmaf(cc4[j].y, nsr, pyi));
                }
                pyr += __shfl_xor(pyr, 1); pyi += __shfl_xor(pyi, 1);
                pyr += __shfl_xor(pyr, 2); pyi += __shfl_xor(pyi, 2);
                if (q == 0) {
                    float2 a = ys[c0q][tt];
                    a.x += pyr; a.y += pyi;
                    ys[c0q][tt] = a;
                }
            }
        }
    }
    __syncthreads();

    // ---- final: D-skip + gelu + bf16 pack + coalesced stores ----
    {
        const float dv = dsh;
        unsigned short* yrp = y + ((size_t)b * 512 + h) * 2048 + tid * 8;
        unsigned short* yip = yrp + 256 * 2048;
        short8 vr8, vi8;
#pragma unroll
        for (int j = 0; j < 8; ++j) {
            const float2 yv = ys[c0q][t0q + j];
            const float2 uv = us[c0q][t0q + j];
            ((unsigned short*)&vr8)[j] = f2bf(gelu_tanh(__builtin_fmaf(dv, uv.x, yv.x)));
            ((unsigned short*)&vi8)[j] = f2bf(gelu_tanh(__builtin_fmaf(dv, uv.y, yv.y)));
        }
        *(short8*)yrp = vr8;
        *(short8*)yip = vi8;
    }
}

// ---------- residual + channel LayerNorm (fp32 planes) ----------
__global__ __launch_bounds__(256) void ln_k(
    const float* __restrict__ o, float* __restrict__ z,
    const float* __restrict__ gamr, const float* __restrict__ gami,
    const float* __restrict__ betr, const float* __restrict__ beti, int l)
{
    const int tt = blockIdx.x, b = blockIdx.y, comp = blockIdx.z;
    const int tid = threadIdx.x;
    const int tloc = tid & 31, gq = tid >> 5;
    __shared__ float tile[256][33];
    __shared__ float red[2][8][32];
    __shared__ float stat[2][32];
    const int t0 = tt * 32;
    const size_t base = ((size_t)b * 512 + comp * 256) * 2048 + t0 + tloc;

#pragma unroll 4
    for (int j = 0; j < 32; ++j) {
        const int g = j * 8 + gq;
        const size_t idx = base + (size_t)g * 2048;
        tile[g][tloc] = o[idx] + z[idx];
    }
    __syncthreads();
    float s = 0.f, sq = 0.f;
#pragma unroll 4
    for (int g2 = 0; g2 < 32; ++g2) {
        const float v = tile[gq * 32 + g2][tloc];
        s += v; sq += v * v;
    }
    red[0][gq][tloc] = s; red[1][gq][tloc] = sq;
    __syncthreads();
    if (tid < 32) {
        float S = 0.f, SQ = 0.f;
#pragma unroll
        for (int q = 0; q < 8; ++q) { S += red[0][q][tid]; SQ += red[1][q][tid]; }
        const float m = S * (1.f / 256.f);
        const float var = SQ * (1.f / 256.f) - m * m;
        stat[0][tid] = m;
        stat[1][tid] = rsqrtf(var + 1e-5f);
    }
    __syncthreads();
    const float* gam = (comp ? gami : gamr) + l * 256;
    const float* bet = (comp ? beti : betr) + l * 256;
    const float m = stat[0][tloc], rs = stat[1][tloc];
#pragma unroll 4
    for (int j = 0; j < 32; ++j) {
        const int g = j * 8 + gq;
        z[base + (size_t)g * 2048] = (tile[g][tloc] - m) * rs * gam[g] + bet[g];
    }
}

extern "C" void kernel_launch(void* const* d_in, const int* in_sizes, int n_in,
                              void* d_out, int out_size, void* d_ws, size_t ws_size,
                              hipStream_t stream)
{
    const float* x        = (const float*)d_in[0];
    const float* enc_Wr   = (const float*)d_in[1];
    const float* enc_Wi   = (const float*)d_in[2];
    const float* enc_br   = (const float*)d_in[3];
    const float* enc_bi   = (const float*)d_in[4];
    const float* log_dt   = (const float*)d_in[5];
    const float* log_A_r  = (const float*)d_in[6];
    const float* A_imag   = (const float*)d_in[7];
    const float* C_r      = (const float*)d_in[8];
    const float* C_i      = (const float*)d_in[9];
    const float* Dp       = (const float*)d_in[10];
    const float* out_Wr   = (const float*)d_in[11];
    const float* out_Wi   = (const float*)d_in[12];
    const float* out_br   = (const float*)d_in[13];
    const float* out_bi   = (const float*)d_in[14];
    const float* ln_gr    = (const float*)d_in[15];
    const float* ln_gi    = (const float*)d_in[16];
    const float* ln_br    = (const float*)d_in[17];
    const float* ln_bi    = (const float*)d_in[18];
    const float* dec_Wr   = (const float*)d_in[19];
    const float* dec_Wi   = (const float*)d_in[20];
    const float* dec_br   = (const float*)d_in[21];
    const float* dec_bi   = (const float*)d_in[22];

    // ---- workspace layout (bytes) ----
    uint8_t* W = (uint8_t*)d_ws;
    float* z             = (float*)W;                       // 33,554,432
    unsigned short* zp   = (unsigned short*)(W + 33554432); // 16,777,216
    unsigned short* A_enc= (unsigned short*)(W + 50331648); // 512x1056x2  = 1,081,344
    unsigned short* A_lay= (unsigned short*)(W + 51412992); // 4x512x512x2 = 2,097,152
    unsigned short* A_dec= (unsigned short*)(W + 53510144); // 1152x512x2  = 1,179,648
    float* b_enc         = (float*)(W + 54689792);          // 512 f
    float* b_lay         = (float*)(W + 54691840);          // 2048 f
    float* b_dec         = (float*)(W + 54700032);          // 1028 f

    // ---- d_out doubles as scratch (67.37 MB total) ----
    float* o            = (float*)d_out;                                   // 33,554,432
    unsigned short* y   = (unsigned short*)((uint8_t*)d_out + 33554432);   // 16,777,216
    unsigned short* yp  = (unsigned short*)((uint8_t*)d_out + 50331648);   // 16,777,216
    unsigned short* xp  = (unsigned short*)d_out;  // 34,603,008; dead after encoder GEMM

    // ---- build weights/biases ----
    buildw_k<<<2112, 256, 0, stream>>>(enc_Wr, enc_Wi, A_enc, 256, 514, 528, 1056, 512);
    for (int l = 0; l < 4; ++l)
        buildw_k<<<1024, 256, 0, stream>>>(out_Wr + (size_t)l * 65536, out_Wi + (size_t)l * 65536,
                                           A_lay + (size_t)l * 262144, 256, 256, 256, 512, 512);
    buildw_k<<<2304, 256, 0, stream>>>(dec_Wr, dec_Wi, A_dec, 514, 256, 256, 512, 1152);
    build_bias_k<<<2, 256, 0, stream>>>(enc_br, enc_bi, b_enc, 256);
    for (int l = 0; l < 4; ++l)
        build_bias_k<<<2, 256, 0, stream>>>(out_br + l * 256, out_bi + l * 256, b_lay + l * 512, 256);
    build_bias_k<<<5, 256, 0, stream>>>(dec_br, dec_bi, b_dec, 514);

    // ---- encoder: pack x -> xp, GEMM -> z ----
    packx_k<<<dim3(32, 9, 8), 256, 0, stream>>>(x, xp);
    mgemm_k<0><<<dim3(4, 16, 8), 256, 0, stream>>>(A_enc, b_enc, xp, z, 512, 1056);

    // ---- layers ----
    for (int l = 0; l < 4; ++l) {
        s4scan_k<<<dim3(256, 8), 256, 0, stream>>>(z, y, log_dt, log_A_r, A_imag, C_r, C_i, Dp, l);
        tr_k<0><<<dim3(32, 8, 8), 256, 0, stream>>>(y, yp);
        mgemm_k<0><<<dim3(4, 16, 8), 256, 0, stream>>>(A_lay + (size_t)l * 262144,
                                                       b_lay + l * 512, yp, o, 512, 512);
        ln_k<<<dim3(64, 8, 2), 256, 0, stream>>>(o, z, ln_gr, ln_gi, ln_br, ln_bi, l);
    }

    // ---- decoder: z -> zp, GEMM -> d_out interleaved (overwrites all scratch) ----
    tr_k<1><<<dim3(32, 8, 8), 256, 0, stream>>>(z, zp);
    mgemm_k<1><<<dim3(9, 16, 8), 256, 0, stream>>>(A_dec, b_dec, zp, (float*)d_out, 1028, 512);
}

// Round 3
// 666.212 us; speedup vs baseline: 1.1124x; 1.1007x over previous
//
#include <hip/hip_runtime.h>
#include <cstddef>
#include <cstdint>

// B=8, C=2, Hf=257, T=2048, D_IN=514, DM=256, NL=4, N=32
// Activations: fp32 planes (b, 2*DM=512, T). GEMMs run bf16 MFMA with
// k-major bf16 activation copies (b, T, Kp).

typedef __attribute__((ext_vector_type(8))) short short8;
typedef __attribute__((ext_vector_type(4))) float float4v;

__device__ __forceinline__ unsigned short f2bf(float f) {
    union { float f; unsigned u; } v; v.f = f;
    const unsigned r = v.u + 0x7fffu + ((v.u >> 16) & 1u);  // RNE
    return (unsigned short)(r >> 16);
}

__device__ __forceinline__ float gelu_tanh(float x) {
    const float x3 = x * x * x;
    const float v  = 0.7978845608028654f * (x + 0.044715f * x3);
    const float e  = __expf(2.f * v);
    const float th = 1.f - 2.f / (e + 1.f);
    return 0.5f * x * (1.f + th);
}

// quad-perm DPP add: returns x + x[lane ^ k] for k in {1,2} (pure VALU,
// no LDS-pipe traffic -- replaces __shfl_xor in the sweep2 reduce).
template<int CTL>
__device__ __forceinline__ float dppadd(float x) {
    union { float f; int i; } a, r;
    a.f = x;
    r.i = __builtin_amdgcn_update_dpp(a.i, a.i, CTL, 0xF, 0xF, true);
    return x + r.f;
}
#define DPP_XOR1 0xB1  // quad_perm [1,0,3,2]
#define DPP_XOR2 0x4E  // quad_perm [2,3,0,1]

#define ASYNC_COPY16(gp, lp) __builtin_amdgcn_global_load_lds( \
    (const __attribute__((address_space(1))) unsigned int*)(gp), \
    (__attribute__((address_space(3))) unsigned int*)(lp), 16, 0, 0)

// ---------- builders: bf16 real-rep of complex weights, padded ----------
__global__ __launch_bounds__(256) void buildw_k(
    const float* __restrict__ Wr, const float* __restrict__ Wi,
    unsigned short* __restrict__ A, int G, int H, int Hoff, int Kp, int Mp)
{
    const long long i = (long long)blockIdx.x * 256 + threadIdx.x;
    if (i >= (long long)Mp * Kp) return;
    const int m = (int)(i / Kp), k = (int)(i % Kp);
    float val = 0.f;
    if (m < 2 * G) {
        const int ri = m >= G;
        const int g = m - ri * G;
        const int blk = k >= Hoff;
        const int hh = k - blk * Hoff;
        if (hh < H) {
            const float wr = Wr[(size_t)g * H + hh];
            const float wi = Wi[(size_t)g * H + hh];
            val = ri ? (blk ? wr : wi) : (blk ? -wi : wr);
        }
    }
    A[i] = f2bf(val);
}

__global__ __launch_bounds__(256) void build_bias_k(
    const float* __restrict__ br, const float* __restrict__ bi,
    float* __restrict__ bias, int G)
{
    const int i = blockIdx.x * 256 + threadIdx.x;
    if (i < G) bias[i] = br[i];
    else if (i < 2 * G) bias[i] = bi[i - G];
}

// ---------- encoder input pack: x (b,514,T,2) fp32 -> xp (b,T,1056) bf16 ----------
__global__ __launch_bounds__(256) void packx_k(const float* __restrict__ x,
                                               unsigned short* __restrict__ xp)
{
    const int t0 = blockIdx.x * 64, d0 = blockIdx.y * 64, b = blockIdx.z;
    __shared__ unsigned short tr_[64][72];
    __shared__ unsigned short ti_[64][72];
    const int tid = threadIdx.x;
    const int tp = tid & 31, dl0 = tid >> 5;
#pragma unroll
    for (int p = 0; p < 8; ++p) {
        const int d = dl0 + p * 8;
        const int gd = d0 + d;
        float4 v = make_float4(0.f, 0.f, 0.f, 0.f);
        if (gd < 514) v = *(const float4*)(x + (((size_t)b * 514 + gd) * 2048 + t0 + tp * 2) * 2);
        tr_[tp * 2 + 0][d] = f2bf(v.x); ti_[tp * 2 + 0][d] = f2bf(v.y);
        tr_[tp * 2 + 1][d] = f2bf(v.z); ti_[tp * 2 + 1][d] = f2bf(v.w);
    }
    __syncthreads();
    const int dc = tid & 7;
    const int kloc = d0 + dc * 8;
    if (kloc < 528) {
#pragma unroll
        for (int p = 0; p < 2; ++p) {
            const int t = (tid >> 3) + p * 32;
            const size_t rowb = ((size_t)b * 2048 + t0 + t) * 1056;
            *(short8*)&xp[rowb + kloc]       = *(const short8*)&tr_[t][dc * 8];
            *(short8*)&xp[rowb + 528 + kloc] = *(const short8*)&ti_[t][dc * 8];
        }
    }
}

// ---------- transpose planes (b,512,T) -> k-major (b,T,512) bf16 ----------
template<int SRC32>
__global__ __launch_bounds__(256) void tr_k(const void* __restrict__ src,
                                            unsigned short* __restrict__ dst)
{
    const int t0 = blockIdx.x * 64, k0 = blockIdx.y * 64, b = blockIdx.z;
    __shared__ unsigned short tile[64][72];
    const int tid = threadIdx.x;
    if (SRC32) {
        const float* sf = (const float*)src;
        const int tp = tid & 31, kl0 = tid >> 5;
#pragma unroll
        for (int p = 0; p < 8; ++p) {
            const int kl = kl0 + p * 8;
            const float2 v = *(const float2*)(sf + ((size_t)b * 512 + k0 + kl) * 2048 + t0 + tp * 2);
            tile[tp * 2 + 0][kl] = f2bf(v.x);
            tile[tp * 2 + 1][kl] = f2bf(v.y);
        }
    } else {
        const unsigned short* su = (const unsigned short*)src;
        const int toct = tid & 7, kl0 = tid >> 3;
#pragma unroll
        for (int p = 0; p < 2; ++p) {
            const int kl = kl0 + p * 32;
            const short8 v = *(const short8*)(su + ((size_t)b * 512 + k0 + kl) * 2048 + t0 + toct * 8);
#pragma unroll
            for (int j = 0; j < 8; ++j) tile[toct * 8 + j][kl] = ((const unsigned short*)&v)[j];
        }
    }
    __syncthreads();
    const int dc = tid & 7;
#pragma unroll
    for (int p = 0; p < 2; ++p) {
        const int t = (tid >> 3) + p * 32;
        *(short8*)&dst[((size_t)b * 2048 + t0 + t) * 512 + k0 + dc * 8] = *(const short8*)&tile[t][dc * 8];
    }
}

// ---------- bf16 MFMA GEMM: out(b,M,T) = A(Mp x Kp) * Bm(b,T,Kp)^T + bias ----------
template<int MODE>
__global__ __launch_bounds__(256, 2) void mgemm_k(
    const unsigned short* __restrict__ A, const float* __restrict__ bias,
    const unsigned short* __restrict__ Bm, float* __restrict__ out,
    int M, int Kp)
{
    __shared__ unsigned short As[4096];  // [m 0..127][k 0..31]
    __shared__ unsigned short Bs[4096];  // [t 0..127][k 0..31]
    const int tid = threadIdx.x;
    const int w = tid >> 6, lane = tid & 63;
    const int m0 = blockIdx.x * 128, t0 = blockIdx.y * 128, b = blockIdx.z;
    const int wm = w & 1, wn = w >> 1;

    const unsigned short* Ab = A + (size_t)m0 * Kp;
    const unsigned short* Bb = Bm + ((size_t)b * 2048 + t0) * Kp;

    const int c0 = w * 64 + lane;
    const int r0 = c0 >> 2, q0 = (c0 & 3) * 8;
    const int c1 = c0 + 256;
    const int r1 = c1 >> 2, q1 = (c1 & 3) * 8;
    unsigned short* As0 = &As[(size_t)(w * 64) * 8];
    unsigned short* As1 = &As[(size_t)(w * 64 + 256) * 8];
    unsigned short* Bs0 = &Bs[(size_t)(w * 64) * 8];
    unsigned short* Bs1 = &Bs[(size_t)(w * 64 + 256) * 8];

    float4v acc[4][4];
#pragma unroll
    for (int i = 0; i < 4; ++i)
#pragma unroll
        for (int j = 0; j < 4; ++j) acc[i][j] = (float4v){0.f, 0.f, 0.f, 0.f};

    const int arow = wm * 64 + (lane & 15);
    const int brow = wn * 64 + (lane & 15);
    const int kq = (lane >> 4) * 8;

    for (int k0 = 0; k0 < Kp; k0 += 32) {
        ASYNC_COPY16(Ab + (size_t)r0 * Kp + k0 + q0, As0);
        ASYNC_COPY16(Ab + (size_t)r1 * Kp + k0 + q1, As1);
        ASYNC_COPY16(Bb + (size_t)r0 * Kp + k0 + q0, Bs0);
        ASYNC_COPY16(Bb + (size_t)r1 * Kp + k0 + q1, Bs1);
        __syncthreads();
        short8 af[4], bf[4];
#pragma unroll
        for (int i = 0; i < 4; ++i) af[i] = *(const short8*)&As[(arow + i * 16) * 32 + kq];
#pragma unroll
        for (int j = 0; j < 4; ++j) bf[j] = *(const short8*)&Bs[(brow + j * 16) * 32 + kq];
#pragma unroll
        for (int i = 0; i < 4; ++i)
#pragma unroll
            for (int j = 0; j < 4; ++j)
                acc[i][j] = __builtin_amdgcn_mfma_f32_16x16x32_bf16(af[i], bf[j], acc[i][j], 0, 0, 0);
        __syncthreads();
    }

    const int col = lane & 15;
    const int rq = (lane >> 4) * 4;
#pragma unroll
    for (int i = 0; i < 4; ++i) {
        const int mloc = wm * 64 + i * 16 + rq;
#pragma unroll
        for (int r = 0; r < 4; ++r) {
            const int m = m0 + mloc + r;
            if (MODE == 1 && m >= M) continue;
            const float bs = bias[m];
#pragma unroll
            for (int j = 0; j < 4; ++j) {
                const int t = t0 + wn * 64 + j * 16 + col;
                const float vv = acc[i][j][r] + bs;
                if (MODE == 0) {
                    out[((size_t)b * 512 + m) * 2048 + t] = vv;
                } else {
                    const int comp = m >= 514;
                    const int g = m - 514 * comp;
                    out[(((size_t)b * 514 + g) * 2048 + t) * 2 + comp] = vv;
                }
            }
        }
    }
}

// ---------- S4D diagonal SSM scan + D-skip + gelu -> bf16 planes ----------
// R3: LDS-pipe diet on top of R2's LDS-resident design. R2 counters showed
// VALU issue ~44us but dur 83us: the stall is the LDS pipe -- sweep2's
// 256 shfl_xor/thread (shuffles are ds-ops on CDNA) + 96 bpermutes in
// sweep1 saturate it (~33us/CU). Changes:
//   * sweep2 reduce via DPP quad_perm adds (pure VALU, 0 ds-ops)
//   * sweep2 single 8-mode pass (halves us reads; ys written once, no RMW,
//     no zero-init)
//   * ys aliased over vsh (vsh fully reg-resident at sweep2 start, extra
//     barrier): LDS 51.2 -> ~34.3 KB -> 4 blocks/CU
//   * __launch_bounds__(256,4): VGPR cap 128 for butterfly/sweep ILP
__global__ __launch_bounds__(256, 4) void s4scan_k(
    const float* __restrict__ z, unsigned short* __restrict__ y,
    const float* __restrict__ log_dt, const float* __restrict__ log_A_real,
    const float* __restrict__ A_imag, const float* __restrict__ C_r,
    const float* __restrict__ C_i, const float* __restrict__ Dsk, int l)
{
    const int h = blockIdx.x, b = blockIdx.y;
    const int tid = threadIdx.x;
    const int lane = tid & 63, wv = tid >> 6;
    __shared__ float2 wsh[32], csh[32];
    __shared__ float dsh;
    __shared__ float2 us[64][33];
    // union: vsh2[chunk 0..63][mode 0..31 (+pad)]  then  ys[chunk][tt]
    __shared__ __align__(16) unsigned char uni[64 * 33 * 8];
    float2 (*vsh2)[33] = (float2(*)[33])uni;
    float2 (*ys)[33]   = (float2(*)[33])uni;

    if (tid < 32) {
        const size_t pidx = ((size_t)l * 256 + h) * 32 + tid;
        const float dt = __expf(log_dt[l * 256 + h]);
        const float Ar = -__expf(log_A_real[pidx]);
        const float Ai = A_imag[pidx];
        const float er = __expf(Ar * dt);
        float sv, cv;
        __sincosf(Ai * dt, &sv, &cv);
        const float wr = er * cv, wi = er * sv;
        const float den = 1.f / (Ar * Ar + Ai * Ai);
        const float nr = wr - 1.f, ni = wi;
        const float qr = (nr * Ar + ni * Ai) * den;
        const float qi = (ni * Ar - nr * Ai) * den;
        const float cr = C_r[pidx], ci = C_i[pidx];
        wsh[tid] = make_float2(wr, wi);
        csh[tid] = make_float2(cr * qr - ci * qi, cr * qi + ci * qr);
    }
    if (tid == 32) dsh = Dsk[l * 256 + h];

    // ---- stage u into LDS. Thread tid owns t = tid*8..+8. ----
    const int c0q = tid >> 2, t0q = (tid & 3) * 8;
    {
        const float* zrp = z + ((size_t)b * 512 + h) * 2048 + tid * 8;
        const float* zip = zrp + 256 * 2048;
        const float4 r0 = *(const float4*)zrp, r1 = *(const float4*)(zrp + 4);
        const float4 i0 = *(const float4*)zip, i1 = *(const float4*)(zip + 4);
        float2* up = &us[c0q][t0q];
        up[0] = make_float2(r0.x, i0.x); up[1] = make_float2(r0.y, i0.y);
        up[2] = make_float2(r0.z, i0.z); up[3] = make_float2(r0.w, i0.w);
        up[4] = make_float2(r1.x, i1.x); up[5] = make_float2(r1.y, i1.y);
        up[6] = make_float2(r1.z, i1.z); up[7] = make_float2(r1.w, i1.w);
    }
    __syncthreads();

    // ---- sweep 1: chunk-local finals + butterfly -> exclusive states ----
    {
        float2 w8[8], x8[8];
#pragma unroll
        for (int j = 0; j < 8; ++j) {
            w8[j] = wsh[wv * 8 + j];
            x8[j] = make_float2(0.f, 0.f);
        }
#pragma unroll 8
        for (int tt = 0; tt < 32; ++tt) {
            const float2 u = us[lane][tt];
#pragma unroll
            for (int j = 0; j < 8; ++j) {
                const float nxr = __builtin_fmaf(w8[j].x, x8[j].x, __builtin_fmaf(-w8[j].y, x8[j].y, u.x));
                const float nxi = __builtin_fmaf(w8[j].x, x8[j].y, __builtin_fmaf(w8[j].y, x8[j].x, u.y));
                x8[j].x = nxr; x8[j].y = nxi;
            }
        }
#pragma unroll
        for (int j = 0; j < 8; ++j) {
            // f = w^32
            float fr = w8[j].x, fi = w8[j].y;
#pragma unroll
            for (int s = 0; s < 5; ++s) { const float a2 = fr * fr - fi * fi, b2 = 2.f * fr * fi; fr = a2; fi = b2; }
            // inclusive wave prefix over chunk-final states with multiplier f
            float qrv = x8[j].x, qiv = x8[j].y, pr = fr, pi = fi;
#pragma unroll
            for (int s = 0; s < 6; ++s) {
                const int d = 1 << s;
                const float sr = __shfl_up(qrv, (unsigned)d);
                const float si = __shfl_up(qiv, (unsigned)d);
                if (lane >= d) {
                    qrv += pr * sr - pi * si;
                    qiv += pr * si + pi * sr;
                }
                const float a2 = pr * pr - pi * pi, b2 = 2.f * pr * pi;
                pr = a2; pi = b2;
            }
            float vr = __shfl_up(qrv, 1u);
            float vi = __shfl_up(qiv, 1u);
            if (lane == 0) { vr = 0.f; vi = 0.f; }
            vsh2[lane][wv * 8 + j] = make_float2(vr, vi);
        }
    }
    __syncthreads();

    // ---- sweep 2: single 8-mode pass, DPP reduce, ys written once ----
    {
        const int q = tid & 3;
        float2 w8[8], c8[8], s8[8];
#pragma unroll
        for (int j = 0; j < 8; ++j) {
            const int n = q * 8 + j;
            w8[j] = wsh[n];
            c8[j] = csh[n];
            s8[j] = vsh2[c0q][n];
        }
        __syncthreads();  // vsh2 fully in regs; ys may now overwrite it
#pragma unroll 4
        for (int tt = 0; tt < 32; ++tt) {
            const float2 u = us[c0q][tt];
            float pyr = 0.f, pyi = 0.f;
#pragma unroll
            for (int j = 0; j < 8; ++j) {
                const float nsr = __builtin_fmaf(w8[j].x, s8[j].x, __builtin_fmaf(-w8[j].y, s8[j].y, u.x));
                const float nsi = __builtin_fmaf(w8[j].x, s8[j].y, __builtin_fmaf(w8[j].y, s8[j].x, u.y));
                s8[j].x = nsr; s8[j].y = nsi;
                pyr = __builtin_fmaf(c8[j].x, nsr, __builtin_fmaf(-c8[j].y, nsi, pyr));
                pyi = __builtin_fmaf(c8[j].x, nsi, __builtin_fmaf(c8[j].y, nsr, pyi));
            }
            pyr = dppadd<DPP_XOR1>(pyr); pyr = dppadd<DPP_XOR2>(pyr);
            pyi = dppadd<DPP_XOR1>(pyi); pyi = dppadd<DPP_XOR2>(pyi);
            if (q == 0) ys[c0q][tt] = make_float2(pyr, pyi);
        }
    }
    __syncthreads();

    // ---- final: D-skip + gelu + bf16 pack + coalesced stores ----
    {
        const float dv = dsh;
        unsigned short* yrp = y + ((size_t)b * 512 + h) * 2048 + tid * 8;
        unsigned short* yip = yrp + 256 * 2048;
        short8 vr8, vi8;
#pragma unroll
        for (int j = 0; j < 8; ++j) {
            const float2 yv = ys[c0q][t0q + j];
            const float2 uv = us[c0q][t0q + j];
            ((unsigned short*)&vr8)[j] = f2bf(gelu_tanh(__builtin_fmaf(dv, uv.x, yv.x)));
            ((unsigned short*)&vi8)[j] = f2bf(gelu_tanh(__builtin_fmaf(dv, uv.y, yv.y)));
        }
        *(short8*)yrp = vr8;
        *(short8*)yip = vi8;
    }
}

// ---------- residual + channel LayerNorm (fp32 planes) ----------
__global__ __launch_bounds__(256) void ln_k(
    const float* __restrict__ o, float* __restrict__ z,
    const float* __restrict__ gamr, const float* __restrict__ gami,
    const float* __restrict__ betr, const float* __restrict__ beti, int l)
{
    const int tt = blockIdx.x, b = blockIdx.y, comp = blockIdx.z;
    const int tid = threadIdx.x;
    const int tloc = tid & 31, gq = tid >> 5;
    __shared__ float tile[256][33];
    __shared__ float red[2][8][32];
    __shared__ float stat[2][32];
    const int t0 = tt * 32;
    const size_t base = ((size_t)b * 512 + comp * 256) * 2048 + t0 + tloc;

#pragma unroll 4
    for (int j = 0; j < 32; ++j) {
        const int g = j * 8 + gq;
        const size_t idx = base + (size_t)g * 2048;
        tile[g][tloc] = o[idx] + z[idx];
    }
    __syncthreads();
    float s = 0.f, sq = 0.f;
#pragma unroll 4
    for (int g2 = 0; g2 < 32; ++g2) {
        const float v = tile[gq * 32 + g2][tloc];
        s += v; sq += v * v;
    }
    red[0][gq][tloc] = s; red[1][gq][tloc] = sq;
    __syncthreads();
    if (tid < 32) {
        float S = 0.f, SQ = 0.f;
#pragma unroll
        for (int q = 0; q < 8; ++q) { S += red[0][q][tid]; SQ += red[1][q][tid]; }
        const float m = S * (1.f / 256.f);
        const float var = SQ * (1.f / 256.f) - m * m;
        stat[0][tid] = m;
        stat[1][tid] = rsqrtf(var + 1e-5f);
    }
    __syncthreads();
    const float* gam = (comp ? gami : gamr) + l * 256;
    const float* bet = (comp ? beti : betr) + l * 256;
    const float m = stat[0][tloc], rs = stat[1][tloc];
#pragma unroll 4
    for (int j = 0; j < 32; ++j) {
        const int g = j * 8 + gq;
        z[base + (size_t)g * 2048] = (tile[g][tloc] - m) * rs * gam[g] + bet[g];
    }
}

extern "C" void kernel_launch(void* const* d_in, const int* in_sizes, int n_in,
                              void* d_out, int out_size, void* d_ws, size_t ws_size,
                              hipStream_t stream)
{
    const float* x        = (const float*)d_in[0];
    const float* enc_Wr   = (const float*)d_in[1];
    const float* enc_Wi   = (const float*)d_in[2];
    const float* enc_br   = (const float*)d_in[3];
    const float* enc_bi   = (const float*)d_in[4];
    const float* log_dt   = (const float*)d_in[5];
    const float* log_A_r  = (const float*)d_in[6];
    const float* A_imag   = (const float*)d_in[7];
    const float* C_r      = (const float*)d_in[8];
    const float* C_i      = (const float*)d_in[9];
    const float* Dp       = (const float*)d_in[10];
    const float* out_Wr   = (const float*)d_in[11];
    const float* out_Wi   = (const float*)d_in[12];
    const float* out_br   = (const float*)d_in[13];
    const float* out_bi   = (const float*)d_in[14];
    const float* ln_gr    = (const float*)d_in[15];
    const float* ln_gi    = (const float*)d_in[16];
    const float* ln_br    = (const float*)d_in[17];
    const float* ln_bi    = (const float*)d_in[18];
    const float* dec_Wr   = (const float*)d_in[19];
    const float* dec_Wi   = (const float*)d_in[20];
    const float* dec_br   = (const float*)d_in[21];
    const float* dec_bi   = (const float*)d_in[22];

    // ---- workspace layout (bytes) ----
    uint8_t* W = (uint8_t*)d_ws;
    float* z             = (float*)W;                       // 33,554,432
    unsigned short* zp   = (unsigned short*)(W + 33554432); // 16,777,216
    unsigned short* A_enc= (unsigned short*)(W + 50331648); // 512x1056x2  = 1,081,344
    unsigned short* A_lay= (unsigned short*)(W + 51412992); // 4x512x512x2 = 2,097,152
    unsigned short* A_dec= (unsigned short*)(W + 53510144); // 1152x512x2  = 1,179,648
    float* b_enc         = (float*)(W + 54689792);          // 512 f
    float* b_lay         = (float*)(W + 54691840);          // 2048 f
    float* b_dec         = (float*)(W + 54700032);          // 1028 f

    // ---- d_out doubles as scratch (67.37 MB total) ----
    float* o            = (float*)d_out;                                   // 33,554,432
    unsigned short* y   = (unsigned short*)((uint8_t*)d_out + 33554432);   // 16,777,216
    unsigned short* yp  = (unsigned short*)((uint8_t*)d_out + 50331648);   // 16,777,216
    unsigned short* xp  = (unsigned short*)d_out;  // 34,603,008; dead after encoder GEMM

    // ---- build weights/biases ----
    buildw_k<<<2112, 256, 0, stream>>>(enc_Wr, enc_Wi, A_enc, 256, 514, 528, 1056, 512);
    for (int l = 0; l < 4; ++l)
        buildw_k<<<1024, 256, 0, stream>>>(out_Wr + (size_t)l * 65536, out_Wi + (size_t)l * 65536,
                                           A_lay + (size_t)l * 262144, 256, 256, 256, 512, 512);
    buildw_k<<<2304, 256, 0, stream>>>(dec_Wr, dec_Wi, A_dec, 514, 256, 256, 512, 1152);
    build_bias_k<<<2, 256, 0, stream>>>(enc_br, enc_bi, b_enc, 256);
    for (int l = 0; l < 4; ++l)
        build_bias_k<<<2, 256, 0, stream>>>(out_br + l * 256, out_bi + l * 256, b_lay + l * 512, 256);
    build_bias_k<<<5, 256, 0, stream>>>(dec_br, dec_bi, b_dec, 514);

    // ---- encoder: pack x -> xp, GEMM -> z ----
    packx_k<<<dim3(32, 9, 8), 256, 0, stream>>>(x, xp);
    mgemm_k<0><<<dim3(4, 16, 8), 256, 0, stream>>>(A_enc, b_enc, xp, z, 512, 1056);

    // ---- layers ----
    for (int l = 0; l < 4; ++l) {
        s4scan_k<<<dim3(256, 8), 256, 0, stream>>>(z, y, log_dt, log_A_r, A_imag, C_r, C_i, Dp, l);
        tr_k<0><<<dim3(32, 8, 8), 256, 0, stream>>>(y, yp);
        mgemm_k<0><<<dim3(4, 16, 8), 256, 0, stream>>>(A_lay + (size_t)l * 262144,
                                                       b_lay + l * 512, yp, o, 512, 512);
        ln_k<<<dim3(64, 8, 2), 256, 0, stream>>>(o, z, ln_gr, ln_gi, ln_br, ln_bi, l);
    }

    // ---- decoder: z -> zp, GEMM -> d_out interleaved (overwrites all scratch) ----
    tr_k<1><<<dim3(32, 8, 8), 256, 0, stream>>>(z, zp);
    mgemm_k<1><<<dim3(9, 16, 8), 256, 0, stream>>>(A_dec, b_dec, zp, (float*)d_out, 1028, 512);
}

// Round 4
// 622.944 us; speedup vs baseline: 1.1897x; 1.0695x over previous
//
#include <hip/hip_runtime.h>
#include <cstddef>
#include <cstdint>

// B=8, C=2, Hf=257, T=2048, D_IN=514, DM=256, NL=4, N=32
// Activations: fp32 planes (b, 2*DM=512, T). GEMMs run bf16 MFMA with
// k-major bf16 activation copies (b, T, Kp).

typedef __attribute__((ext_vector_type(8))) short short8;
typedef __attribute__((ext_vector_type(4))) float float4v;

__device__ __forceinline__ unsigned short f2bf(float f) {
    union { float f; unsigned u; } v; v.f = f;
    const unsigned r = v.u + 0x7fffu + ((v.u >> 16) & 1u);  // RNE
    return (unsigned short)(r >> 16);
}

__device__ __forceinline__ float gelu_tanh(float x) {
    const float x3 = x * x * x;
    const float v  = 0.7978845608028654f * (x + 0.044715f * x3);
    const float e  = __expf(2.f * v);
    const float th = 1.f - 2.f / (e + 1.f);
    return 0.5f * x * (1.f + th);
}

// quad-perm DPP add: returns x + x[lane ^ k] for k in {1,2} (pure VALU,
// no LDS-pipe traffic).
template<int CTL>
__device__ __forceinline__ float dppadd(float x) {
    union { float f; int i; } a, r;
    a.f = x;
    r.i = __builtin_amdgcn_update_dpp(a.i, a.i, CTL, 0xF, 0xF, true);
    return x + r.f;
}
#define DPP_XOR1 0xB1  // quad_perm [1,0,3,2]
#define DPP_XOR2 0x4E  // quad_perm [2,3,0,1]

#define ASYNC_COPY16(gp, lp) __builtin_amdgcn_global_load_lds( \
    (const __attribute__((address_space(1))) unsigned int*)(gp), \
    (__attribute__((address_space(3))) unsigned int*)(lp), 16, 0, 0)

// ---------- builders: bf16 real-rep of complex weights, padded ----------
__global__ __launch_bounds__(256) void buildw_k(
    const float* __restrict__ Wr, const float* __restrict__ Wi,
    unsigned short* __restrict__ A, int G, int H, int Hoff, int Kp, int Mp)
{
    const long long i = (long long)blockIdx.x * 256 + threadIdx.x;
    if (i >= (long long)Mp * Kp) return;
    const int m = (int)(i / Kp), k = (int)(i % Kp);
    float val = 0.f;
    if (m < 2 * G) {
        const int ri = m >= G;
        const int g = m - ri * G;
        const int blk = k >= Hoff;
        const int hh = k - blk * Hoff;
        if (hh < H) {
            const float wr = Wr[(size_t)g * H + hh];
            const float wi = Wi[(size_t)g * H + hh];
            val = ri ? (blk ? wr : wi) : (blk ? -wi : wr);
        }
    }
    A[i] = f2bf(val);
}

// layer weights: 4 layers in one launch (blockIdx.y = l), G=H=Hoff=256, Kp=Mp=512
__global__ __launch_bounds__(256) void buildwL_k(
    const float* __restrict__ Wr0, const float* __restrict__ Wi0,
    unsigned short* __restrict__ A0)
{
    const int l = blockIdx.y;
    const float* Wr = Wr0 + (size_t)l * 65536;
    const float* Wi = Wi0 + (size_t)l * 65536;
    unsigned short* A = A0 + (size_t)l * 262144;
    const int i = blockIdx.x * 256 + threadIdx.x;
    const int m = i >> 9, k = i & 511;
    const int ri = m >= 256;
    const int g = m & 255;
    const int blk = k >> 8;
    const int hh = k & 255;
    const float wr = Wr[(size_t)g * 256 + hh];
    const float wi = Wi[(size_t)g * 256 + hh];
    const float val = ri ? (blk ? wr : wi) : (blk ? -wi : wr);
    A[i] = f2bf(val);
}

__global__ __launch_bounds__(256) void build_bias_k(
    const float* __restrict__ br, const float* __restrict__ bi,
    float* __restrict__ bias, int G)
{
    const int i = blockIdx.x * 256 + threadIdx.x;
    if (i < G) bias[i] = br[i];
    else if (i < 2 * G) bias[i] = bi[i - G];
}

// layer biases: 4 layers in one launch (blockIdx.y = l), G=256
__global__ __launch_bounds__(256) void build_biasL_k(
    const float* __restrict__ br0, const float* __restrict__ bi0,
    float* __restrict__ bias0)
{
    const int l = blockIdx.y;
    const int i = blockIdx.x * 256 + threadIdx.x;
    const float* br = br0 + l * 256;
    const float* bi = bi0 + l * 256;
    float* bias = bias0 + l * 512;
    if (i < 256) bias[i] = br[i];
    else bias[i] = bi[i - 256];
}

// ---------- encoder input pack: x (b,514,T,2) fp32 -> xp (b,T,1056) bf16 ----------
__global__ __launch_bounds__(256) void packx_k(const float* __restrict__ x,
                                               unsigned short* __restrict__ xp)
{
    const int t0 = blockIdx.x * 64, d0 = blockIdx.y * 64, b = blockIdx.z;
    __shared__ unsigned short tr_[64][72];
    __shared__ unsigned short ti_[64][72];
    const int tid = threadIdx.x;
    const int tp = tid & 31, dl0 = tid >> 5;
#pragma unroll
    for (int p = 0; p < 8; ++p) {
        const int d = dl0 + p * 8;
        const int gd = d0 + d;
        float4 v = make_float4(0.f, 0.f, 0.f, 0.f);
        if (gd < 514) v = *(const float4*)(x + (((size_t)b * 514 + gd) * 2048 + t0 + tp * 2) * 2);
        tr_[tp * 2 + 0][d] = f2bf(v.x); ti_[tp * 2 + 0][d] = f2bf(v.y);
        tr_[tp * 2 + 1][d] = f2bf(v.z); ti_[tp * 2 + 1][d] = f2bf(v.w);
    }
    __syncthreads();
    const int dc = tid & 7;
    const int kloc = d0 + dc * 8;
    if (kloc < 528) {
#pragma unroll
        for (int p = 0; p < 2; ++p) {
            const int t = (tid >> 3) + p * 32;
            const size_t rowb = ((size_t)b * 2048 + t0 + t) * 1056;
            *(short8*)&xp[rowb + kloc]       = *(const short8*)&tr_[t][dc * 8];
            *(short8*)&xp[rowb + 528 + kloc] = *(const short8*)&ti_[t][dc * 8];
        }
    }
}

// ---------- transpose planes (b,512,T) -> k-major (b,T,512) bf16 ----------
template<int SRC32>
__global__ __launch_bounds__(256) void tr_k(const void* __restrict__ src,
                                            unsigned short* __restrict__ dst)
{
    const int t0 = blockIdx.x * 64, k0 = blockIdx.y * 64, b = blockIdx.z;
    __shared__ unsigned short tile[64][72];
    const int tid = threadIdx.x;
    if (SRC32) {
        const float* sf = (const float*)src;
        const int tp = tid & 31, kl0 = tid >> 5;
#pragma unroll
        for (int p = 0; p < 8; ++p) {
            const int kl = kl0 + p * 8;
            const float2 v = *(const float2*)(sf + ((size_t)b * 512 + k0 + kl) * 2048 + t0 + tp * 2);
            tile[tp * 2 + 0][kl] = f2bf(v.x);
            tile[tp * 2 + 1][kl] = f2bf(v.y);
        }
    } else {
        const unsigned short* su = (const unsigned short*)src;
        const int toct = tid & 7, kl0 = tid >> 3;
#pragma unroll
        for (int p = 0; p < 2; ++p) {
            const int kl = kl0 + p * 32;
            const short8 v = *(const short8*)(su + ((size_t)b * 512 + k0 + kl) * 2048 + t0 + toct * 8);
#pragma unroll
            for (int j = 0; j < 8; ++j) tile[toct * 8 + j][kl] = ((const unsigned short*)&v)[j];
        }
    }
    __syncthreads();
    const int dc = tid & 7;
#pragma unroll
    for (int p = 0; p < 2; ++p) {
        const int t = (tid >> 3) + p * 32;
        *(short8*)&dst[((size_t)b * 2048 + t0 + t) * 512 + k0 + dc * 8] = *(const short8*)&tile[t][dc * 8];
    }
}

// ---------- bf16 MFMA GEMM (encoder/decoder): out = A * Bm^T + bias ----------
template<int MODE>
__global__ __launch_bounds__(256, 2) void mgemm_k(
    const unsigned short* __restrict__ A, const float* __restrict__ bias,
    const unsigned short* __restrict__ Bm, float* __restrict__ out,
    int M, int Kp)
{
    __shared__ unsigned short As[4096];  // [m 0..127][k 0..31]
    __shared__ unsigned short Bs[4096];  // [t 0..127][k 0..31]
    const int tid = threadIdx.x;
    const int w = tid >> 6, lane = tid & 63;
    const int m0 = blockIdx.x * 128, t0 = blockIdx.y * 128, b = blockIdx.z;
    const int wm = w & 1, wn = w >> 1;

    const unsigned short* Ab = A + (size_t)m0 * Kp;
    const unsigned short* Bb = Bm + ((size_t)b * 2048 + t0) * Kp;

    const int c0 = w * 64 + lane;
    const int r0 = c0 >> 2, q0 = (c0 & 3) * 8;
    const int c1 = c0 + 256;
    const int r1 = c1 >> 2, q1 = (c1 & 3) * 8;
    unsigned short* As0 = &As[(size_t)(w * 64) * 8];
    unsigned short* As1 = &As[(size_t)(w * 64 + 256) * 8];
    unsigned short* Bs0 = &Bs[(size_t)(w * 64) * 8];
    unsigned short* Bs1 = &Bs[(size_t)(w * 64 + 256) * 8];

    float4v acc[4][4];
#pragma unroll
    for (int i = 0; i < 4; ++i)
#pragma unroll
        for (int j = 0; j < 4; ++j) acc[i][j] = (float4v){0.f, 0.f, 0.f, 0.f};

    const int arow = wm * 64 + (lane & 15);
    const int brow = wn * 64 + (lane & 15);
    const int kq = (lane >> 4) * 8;

    for (int k0 = 0; k0 < Kp; k0 += 32) {
        ASYNC_COPY16(Ab + (size_t)r0 * Kp + k0 + q0, As0);
        ASYNC_COPY16(Ab + (size_t)r1 * Kp + k0 + q1, As1);
        ASYNC_COPY16(Bb + (size_t)r0 * Kp + k0 + q0, Bs0);
        ASYNC_COPY16(Bb + (size_t)r1 * Kp + k0 + q1, Bs1);
        __syncthreads();
        short8 af[4], bf[4];
#pragma unroll
        for (int i = 0; i < 4; ++i) af[i] = *(const short8*)&As[(arow + i * 16) * 32 + kq];
#pragma unroll
        for (int j = 0; j < 4; ++j) bf[j] = *(const short8*)&Bs[(brow + j * 16) * 32 + kq];
#pragma unroll
        for (int i = 0; i < 4; ++i)
#pragma unroll
            for (int j = 0; j < 4; ++j)
                acc[i][j] = __builtin_amdgcn_mfma_f32_16x16x32_bf16(af[i], bf[j], acc[i][j], 0, 0, 0);
        __syncthreads();
    }

    const int col = lane & 15;
    const int rq = (lane >> 4) * 4;
#pragma unroll
    for (int i = 0; i < 4; ++i) {
        const int mloc = wm * 64 + i * 16 + rq;
#pragma unroll
        for (int r = 0; r < 4; ++r) {
            const int m = m0 + mloc + r;
            if (MODE == 1 && m >= M) continue;
            const float bs = bias[m];
#pragma unroll
            for (int j = 0; j < 4; ++j) {
                const int t = t0 + wn * 64 + j * 16 + col;
                const float vv = acc[i][j][r] + bs;
                if (MODE == 0) {
                    out[((size_t)b * 512 + m) * 2048 + t] = vv;
                } else {
                    const int comp = m >= 514;
                    const int g = m - 514 * comp;
                    out[(((size_t)b * 514 + g) * 2048 + t) * 2 + comp] = vv;
                }
            }
        }
    }
}

// ---------- fused layer GEMM + residual + channel LayerNorm ----------
// R4: replaces {mgemm_k<0> -> o ; ln_k(o,z)} per layer. Block = full M=512
// x 64-t tile (grid 32 x 8 = 256 = 1 block/CU, 512 threads = 8 waves, wave w
// owns m in [w*64, w*64+64)). B tile (64t x 512k bf16, padded rows 1040B)
// staged ONCE via reg->LDS -- no per-K-step barriers. A fragments are read
// directly from global each K-step (16B/lane; 4 lanes share one 64B line =
// 100% utilization; A_lay is 512KB/layer -> L2-resident). Epilogue computes
// v = acc + bias + z_old in-register, reduces per-(t,comp) sum/sumsq via
// 2x shfl_xor + LDS, then writes z = LN(v)*gamma+beta. Eliminates the o
// plane (67MB traffic/layer) and the separate ln_k launch.
__global__ __launch_bounds__(512, 2) void mgemmln_k(
    const unsigned short* __restrict__ A, const float* __restrict__ bias,
    const unsigned short* __restrict__ Bm, float* __restrict__ z,
    const float* __restrict__ gamr, const float* __restrict__ gami,
    const float* __restrict__ betr, const float* __restrict__ beti, int l)
{
    __shared__ unsigned short Bs[64][520];   // 64 t rows, 512 k + 8 pad (1040B)
    __shared__ float biasS[512], gamS[512], betS[512];
    __shared__ float sred[8][64][2];
    __shared__ float sstat[2][64][2];
    const int tid = threadIdx.x;
    const int w = tid >> 6, lane = tid & 63;
    const int t0g = blockIdx.x * 64, b = blockIdx.y;

    // ---- stage B (64KB) + per-m params ----
    {
        const unsigned char* src = (const unsigned char*)(Bm + ((size_t)b * 2048 + t0g) * 512);
        unsigned char* dstb = (unsigned char*)&Bs[0][0];
#pragma unroll
        for (int p = 0; p < 8; ++p) {
            const int go = p * 8192 + tid * 16;
            const int t = go >> 10, off = go & 1023;
            *(short8*)(dstb + t * 1040 + off) = *(const short8*)(src + t * 1024 + off);
        }
        const int m = tid, g = m & 255, comp = m >> 8;
        biasS[m] = bias[m];
        gamS[m] = (comp ? gami : gamr)[l * 256 + g];
        betS[m] = (comp ? beti : betr)[l * 256 + g];
    }
    __syncthreads();

    // ---- K-loop: A direct from global (L2-resident), B from LDS ----
    float4v acc[4][4];
#pragma unroll
    for (int i = 0; i < 4; ++i)
#pragma unroll
        for (int j = 0; j < 4; ++j) acc[i][j] = (float4v){0.f, 0.f, 0.f, 0.f};

    const int brow = lane & 15;
    const int kq8 = (lane >> 4) * 8;                       // k-octet within 32
    const unsigned short* Ab = A + ((size_t)(w * 64 + brow)) * 512 + kq8;
    const unsigned char* BsB = (const unsigned char*)&Bs[0][0];

#define LOADF(af_, bf_, k0_) do {                                              \
    _Pragma("unroll")                                                          \
    for (int i = 0; i < 4; ++i)                                                \
        af_[i] = *(const short8*)(Ab + (size_t)i * 16 * 512 + (k0_));          \
    _Pragma("unroll")                                                          \
    for (int j = 0; j < 4; ++j)                                                \
        bf_[j] = *(const short8*)(BsB + (j * 16 + brow) * 1040 + ((k0_) + kq8) * 2); \
} while (0)
#define MFMAS(af_, bf_) do {                                                   \
    _Pragma("unroll")                                                          \
    for (int i = 0; i < 4; ++i)                                                \
        _Pragma("unroll")                                                      \
        for (int j = 0; j < 4; ++j)                                            \
            acc[i][j] = __builtin_amdgcn_mfma_f32_16x16x32_bf16(af_[i], bf_[j], acc[i][j], 0, 0, 0); \
} while (0)

    {
        short8 afA[4], bfA[4], afB[4], bfB[4];
        LOADF(afA, bfA, 0);
#pragma unroll 1
        for (int kk = 0; kk < 16; kk += 2) {
            LOADF(afB, bfB, kk * 32 + 32);
            MFMAS(afA, bfA);
            if (kk + 2 < 16) LOADF(afA, bfA, kk * 32 + 64);
            MFMAS(afB, bfB);
        }
    }
#undef LOADF
#undef MFMAS

    // ---- epilogue: v = acc + bias + z_old, LN stats, normalize, write z ----
    const int q4 = (lane >> 4) * 4;
    float4 b4[4], g4[4], e4[4];
#pragma unroll
    for (int i = 0; i < 4; ++i) {
        const int m0 = w * 64 + i * 16 + q4;
        b4[i] = *(const float4*)&biasS[m0];
        g4[i] = *(const float4*)&gamS[m0];
        e4[i] = *(const float4*)&betS[m0];
    }

    float s1[4], s2[4];
#pragma unroll
    for (int j = 0; j < 4; ++j) { s1[j] = 0.f; s2[j] = 0.f; }
#pragma unroll
    for (int j = 0; j < 4; ++j) {
        const int t = t0g + j * 16 + brow;
#pragma unroll
        for (int i = 0; i < 4; ++i) {
            const int m = w * 64 + i * 16 + q4;
            const float* zp = &z[((size_t)b * 512 + m) * 2048 + t];
            const float bb[4] = {b4[i].x, b4[i].y, b4[i].z, b4[i].w};
#pragma unroll
            for (int r = 0; r < 4; ++r) {
                const float v = acc[i][j][r] + bb[r] + zp[(size_t)r * 2048];
                acc[i][j][r] = v;
                s1[j] += v; s2[j] += v * v;
            }
        }
    }
#pragma unroll
    for (int j = 0; j < 4; ++j) {
        s1[j] += __shfl_xor(s1[j], 16); s2[j] += __shfl_xor(s2[j], 16);
        s1[j] += __shfl_xor(s1[j], 32); s2[j] += __shfl_xor(s2[j], 32);
    }
    if (lane < 16) {
#pragma unroll
        for (int j = 0; j < 4; ++j) {
            sred[w][j * 16 + lane][0] = s1[j];
            sred[w][j * 16 + lane][1] = s2[j];
        }
    }
    __syncthreads();
    if (tid < 128) {
        const int t = tid & 63, comp = tid >> 6;
        float S1 = 0.f, S2 = 0.f;
#pragma unroll
        for (int w2 = 0; w2 < 4; ++w2) {
            S1 += sred[comp * 4 + w2][t][0];
            S2 += sred[comp * 4 + w2][t][1];
        }
        const float mn = S1 * (1.f / 256.f);
        const float var = S2 * (1.f / 256.f) - mn * mn;
        sstat[comp][t][0] = mn;
        sstat[comp][t][1] = rsqrtf(var + 1e-5f);
    }
    __syncthreads();
    const int comp = w >> 2;
#pragma unroll
    for (int j = 0; j < 4; ++j) {
        const int tl = j * 16 + brow;
        const float mn = sstat[comp][tl][0], rs = sstat[comp][tl][1];
        const int t = t0g + tl;
#pragma unroll
        for (int i = 0; i < 4; ++i) {
            const int m = w * 64 + i * 16 + q4;
            float* zp = &z[((size_t)b * 512 + m) * 2048 + t];
            const float gg[4] = {g4[i].x, g4[i].y, g4[i].z, g4[i].w};
            const float ee[4] = {e4[i].x, e4[i].y, e4[i].z, e4[i].w};
#pragma unroll
            for (int r = 0; r < 4; ++r)
                zp[(size_t)r * 2048] = (acc[i][j][r] - mn) * rs * gg[r] + ee[r];
        }
    }
}

// ---------- S4D diagonal SSM scan + D-skip + gelu -> bf16 planes ----------
// R3 design (verified): LDS-resident u, DPP quad-perm reduce, ys aliased
// over vsh, 34.8KB LDS.
__global__ __launch_bounds__(256, 4) void s4scan_k(
    const float* __restrict__ z, unsigned short* __restrict__ y,
    const float* __restrict__ log_dt, const float* __restrict__ log_A_real,
    const float* __restrict__ A_imag, const float* __restrict__ C_r,
    const float* __restrict__ C_i, const float* __restrict__ Dsk, int l)
{
    const int h = blockIdx.x, b = blockIdx.y;
    const int tid = threadIdx.x;
    const int lane = tid & 63, wv = tid >> 6;
    __shared__ float2 wsh[32], csh[32];
    __shared__ float dsh;
    __shared__ float2 us[64][33];
    __shared__ __align__(16) unsigned char uni[64 * 33 * 8];
    float2 (*vsh2)[33] = (float2(*)[33])uni;
    float2 (*ys)[33]   = (float2(*)[33])uni;

    if (tid < 32) {
        const size_t pidx = ((size_t)l * 256 + h) * 32 + tid;
        const float dt = __expf(log_dt[l * 256 + h]);
        const float Ar = -__expf(log_A_real[pidx]);
        const float Ai = A_imag[pidx];
        const float er = __expf(Ar * dt);
        float sv, cv;
        __sincosf(Ai * dt, &sv, &cv);
        const float wr = er * cv, wi = er * sv;
        const float den = 1.f / (Ar * Ar + Ai * Ai);
        const float nr = wr - 1.f, ni = wi;
        const float qr = (nr * Ar + ni * Ai) * den;
        const float qi = (ni * Ar - nr * Ai) * den;
        const float cr = C_r[pidx], ci = C_i[pidx];
        wsh[tid] = make_float2(wr, wi);
        csh[tid] = make_float2(cr * qr - ci * qi, cr * qi + ci * qr);
    }
    if (tid == 32) dsh = Dsk[l * 256 + h];

    const int c0q = tid >> 2, t0q = (tid & 3) * 8;
    {
        const float* zrp = z + ((size_t)b * 512 + h) * 2048 + tid * 8;
        const float* zip = zrp + 256 * 2048;
        const float4 r0 = *(const float4*)zrp, r1 = *(const float4*)(zrp + 4);
        const float4 i0 = *(const float4*)zip, i1 = *(const float4*)(zip + 4);
        float2* up = &us[c0q][t0q];
        up[0] = make_float2(r0.x, i0.x); up[1] = make_float2(r0.y, i0.y);
        up[2] = make_float2(r0.z, i0.z); up[3] = make_float2(r0.w, i0.w);
        up[4] = make_float2(r1.x, i1.x); up[5] = make_float2(r1.y, i1.y);
        up[6] = make_float2(r1.z, i1.z); up[7] = make_float2(r1.w, i1.w);
    }
    __syncthreads();

    // ---- sweep 1: chunk-local finals + butterfly -> exclusive states ----
    {
        float2 w8[8], x8[8];
#pragma unroll
        for (int j = 0; j < 8; ++j) {
            w8[j] = wsh[wv * 8 + j];
            x8[j] = make_float2(0.f, 0.f);
        }
#pragma unroll 8
        for (int tt = 0; tt < 32; ++tt) {
            const float2 u = us[lane][tt];
#pragma unroll
            for (int j = 0; j < 8; ++j) {
                const float nxr = __builtin_fmaf(w8[j].x, x8[j].x, __builtin_fmaf(-w8[j].y, x8[j].y, u.x));
                const float nxi = __builtin_fmaf(w8[j].x, x8[j].y, __builtin_fmaf(w8[j].y, x8[j].x, u.y));
                x8[j].x = nxr; x8[j].y = nxi;
            }
        }
#pragma unroll
        for (int j = 0; j < 8; ++j) {
            float fr = w8[j].x, fi = w8[j].y;
#pragma unroll
            for (int s = 0; s < 5; ++s) { const float a2 = fr * fr - fi * fi, b2 = 2.f * fr * fi; fr = a2; fi = b2; }
            float qrv = x8[j].x, qiv = x8[j].y, pr = fr, pi = fi;
#pragma unroll
            for (int s = 0; s < 6; ++s) {
                const int d = 1 << s;
                const float sr = __shfl_up(qrv, (unsigned)d);
                const float si = __shfl_up(qiv, (unsigned)d);
                if (lane >= d) {
                    qrv += pr * sr - pi * si;
                    qiv += pr * si + pi * sr;
                }
                const float a2 = pr * pr - pi * pi, b2 = 2.f * pr * pi;
                pr = a2; pi = b2;
            }
            float vr = __shfl_up(qrv, 1u);
            float vi = __shfl_up(qiv, 1u);
            if (lane == 0) { vr = 0.f; vi = 0.f; }
            vsh2[lane][wv * 8 + j] = make_float2(vr, vi);
        }
    }
    __syncthreads();

    // ---- sweep 2: single 8-mode pass, DPP reduce, ys written once ----
    {
        const int q = tid & 3;
        float2 w8[8], c8[8], s8[8];
#pragma unroll
        for (int j = 0; j < 8; ++j) {
            const int n = q * 8 + j;
            w8[j] = wsh[n];
            c8[j] = csh[n];
            s8[j] = vsh2[c0q][n];
        }
        __syncthreads();  // vsh2 fully in regs; ys may now overwrite it
#pragma unroll 4
        for (int tt = 0; tt < 32; ++tt) {
            const float2 u = us[c0q][tt];
            float pyr = 0.f, pyi = 0.f;
#pragma unroll
            for (int j = 0; j < 8; ++j) {
                const float nsr = __builtin_fmaf(w8[j].x, s8[j].x, __builtin_fmaf(-w8[j].y, s8[j].y, u.x));
                const float nsi = __builtin_fmaf(w8[j].x, s8[j].y, __builtin_fmaf(w8[j].y, s8[j].x, u.y));
                s8[j].x = nsr; s8[j].y = nsi;
                pyr = __builtin_fmaf(c8[j].x, nsr, __builtin_fmaf(-c8[j].y, nsi, pyr));
                pyi = __builtin_fmaf(c8[j].x, nsi, __builtin_fmaf(c8[j].y, nsr, pyi));
            }
            pyr = dppadd<DPP_XOR1>(pyr); pyr = dppadd<DPP_XOR2>(pyr);
            pyi = dppadd<DPP_XOR1>(pyi); pyi = dppadd<DPP_XOR2>(pyi);
            if (q == 0) ys[c0q][tt] = make_float2(pyr, pyi);
        }
    }
    __syncthreads();

    // ---- final: D-skip + gelu + bf16 pack + coalesced stores ----
    {
        const float dv = dsh;
        unsigned short* yrp = y + ((size_t)b * 512 + h) * 2048 + tid * 8;
        unsigned short* yip = yrp + 256 * 2048;
        short8 vr8, vi8;
#pragma unroll
        for (int j = 0; j < 8; ++j) {
            const float2 yv = ys[c0q][t0q + j];
            const float2 uv = us[c0q][t0q + j];
            ((unsigned short*)&vr8)[j] = f2bf(gelu_tanh(__builtin_fmaf(dv, uv.x, yv.x)));
            ((unsigned short*)&vi8)[j] = f2bf(gelu_tanh(__builtin_fmaf(dv, uv.y, yv.y)));
        }
        *(short8*)yrp = vr8;
        *(short8*)yip = vi8;
    }
}

extern "C" void kernel_launch(void* const* d_in, const int* in_sizes, int n_in,
                              void* d_out, int out_size, void* d_ws, size_t ws_size,
                              hipStream_t stream)
{
    const float* x        = (const float*)d_in[0];
    const float* enc_Wr   = (const float*)d_in[1];
    const float* enc_Wi   = (const float*)d_in[2];
    const float* enc_br   = (const float*)d_in[3];
    const float* enc_bi   = (const float*)d_in[4];
    const float* log_dt   = (const float*)d_in[5];
    const float* log_A_r  = (const float*)d_in[6];
    const float* A_imag   = (const float*)d_in[7];
    const float* C_r      = (const float*)d_in[8];
    const float* C_i      = (const float*)d_in[9];
    const float* Dp       = (const float*)d_in[10];
    const float* out_Wr   = (const float*)d_in[11];
    const float* out_Wi   = (const float*)d_in[12];
    const float* out_br   = (const float*)d_in[13];
    const float* out_bi   = (const float*)d_in[14];
    const float* ln_gr    = (const float*)d_in[15];
    const float* ln_gi    = (const float*)d_in[16];
    const float* ln_br    = (const float*)d_in[17];
    const float* ln_bi    = (const float*)d_in[18];
    const float* dec_Wr   = (const float*)d_in[19];
    const float* dec_Wi   = (const float*)d_in[20];
    const float* dec_br   = (const float*)d_in[21];
    const float* dec_bi   = (const float*)d_in[22];

    // ---- workspace layout (bytes) ----
    uint8_t* W = (uint8_t*)d_ws;
    float* z             = (float*)W;                       // 33,554,432
    unsigned short* zp   = (unsigned short*)(W + 33554432); // 16,777,216
    unsigned short* A_enc= (unsigned short*)(W + 50331648); // 512x1056x2  = 1,081,344
    unsigned short* A_lay= (unsigned short*)(W + 51412992); // 4x512x512x2 = 2,097,152
    unsigned short* A_dec= (unsigned short*)(W + 53510144); // 1152x512x2  = 1,179,648
    float* b_enc         = (float*)(W + 54689792);          // 512 f
    float* b_lay         = (float*)(W + 54691840);          // 2048 f
    float* b_dec         = (float*)(W + 54700032);          // 1028 f

    // ---- d_out doubles as scratch ----
    unsigned short* y   = (unsigned short*)((uint8_t*)d_out + 33554432);   // 16,777,216
    unsigned short* yp  = (unsigned short*)((uint8_t*)d_out + 50331648);   // 16,777,216
    unsigned short* xp  = (unsigned short*)d_out;  // 34,603,008; dead after encoder GEMM

    // ---- build weights/biases ----
    buildw_k<<<2112, 256, 0, stream>>>(enc_Wr, enc_Wi, A_enc, 256, 514, 528, 1056, 512);
    buildwL_k<<<dim3(1024, 4), 256, 0, stream>>>(out_Wr, out_Wi, A_lay);
    buildw_k<<<2304, 256, 0, stream>>>(dec_Wr, dec_Wi, A_dec, 514, 256, 256, 512, 1152);
    build_bias_k<<<2, 256, 0, stream>>>(enc_br, enc_bi, b_enc, 256);
    build_biasL_k<<<dim3(2, 4), 256, 0, stream>>>(out_br, out_bi, b_lay);
    build_bias_k<<<5, 256, 0, stream>>>(dec_br, dec_bi, b_dec, 514);

    // ---- encoder: pack x -> xp, GEMM -> z ----
    packx_k<<<dim3(32, 9, 8), 256, 0, stream>>>(x, xp);
    mgemm_k<0><<<dim3(4, 16, 8), 256, 0, stream>>>(A_enc, b_enc, xp, z, 512, 1056);

    // ---- layers: scan -> transpose -> fused GEMM+residual+LN ----
    for (int l = 0; l < 4; ++l) {
        s4scan_k<<<dim3(256, 8), 256, 0, stream>>>(z, y, log_dt, log_A_r, A_imag, C_r, C_i, Dp, l);
        tr_k<0><<<dim3(32, 8, 8), 256, 0, stream>>>(y, yp);
        mgemmln_k<<<dim3(32, 8), 512, 0, stream>>>(A_lay + (size_t)l * 262144,
                                                   b_lay + l * 512, yp, z,
                                                   ln_gr, ln_gi, ln_br, ln_bi, l);
    }

    // ---- decoder: z -> zp, GEMM -> d_out interleaved ----
    tr_k<1><<<dim3(32, 8, 8), 256, 0, stream>>>(z, zp);
    mgemm_k<1><<<dim3(9, 16, 8), 256, 0, stream>>>(A_dec, b_dec, zp, (float*)d_out, 1028, 512);
}

// Round 5
// 593.318 us; speedup vs baseline: 1.2491x; 1.0499x over previous
//
#include <hip/hip_runtime.h>
#include <cstddef>
#include <cstdint>

// B=8, C=2, Hf=257, T=2048, D_IN=514, DM=256, NL=4, N=32
// Activations: fp32 planes (b, 2*DM=512, T). GEMMs run bf16 MFMA.
// R5: mgemmln stages B directly from t-major y planes (transpose folded
// into the LDS write with XOR swizzle) -- tr_k<0> eliminated.

typedef __attribute__((ext_vector_type(8))) short short8;
typedef __attribute__((ext_vector_type(4))) float float4v;

__device__ __forceinline__ unsigned short f2bf(float f) {
    union { float f; unsigned u; } v; v.f = f;
    const unsigned r = v.u + 0x7fffu + ((v.u >> 16) & 1u);  // RNE
    return (unsigned short)(r >> 16);
}

__device__ __forceinline__ float gelu_tanh(float x) {
    const float x3 = x * x * x;
    const float v  = 0.7978845608028654f * (x + 0.044715f * x3);
    const float e  = __expf(2.f * v);
    const float th = 1.f - 2.f / (e + 1.f);
    return 0.5f * x * (1.f + th);
}

// quad-perm DPP add: returns x + x[lane ^ k] for k in {1,2} (pure VALU).
template<int CTL>
__device__ __forceinline__ float dppadd(float x) {
    union { float f; int i; } a, r;
    a.f = x;
    r.i = __builtin_amdgcn_update_dpp(a.i, a.i, CTL, 0xF, 0xF, true);
    return x + r.f;
}
#define DPP_XOR1 0xB1  // quad_perm [1,0,3,2]
#define DPP_XOR2 0x4E  // quad_perm [2,3,0,1]

#define ASYNC_COPY16(gp, lp) __builtin_amdgcn_global_load_lds( \
    (const __attribute__((address_space(1))) unsigned int*)(gp), \
    (__attribute__((address_space(3))) unsigned int*)(lp), 16, 0, 0)

// ---------- builders: bf16 real-rep of complex weights, padded ----------
__global__ __launch_bounds__(256) void buildw_k(
    const float* __restrict__ Wr, const float* __restrict__ Wi,
    unsigned short* __restrict__ A, int G, int H, int Hoff, int Kp, int Mp)
{
    const long long i = (long long)blockIdx.x * 256 + threadIdx.x;
    if (i >= (long long)Mp * Kp) return;
    const int m = (int)(i / Kp), k = (int)(i % Kp);
    float val = 0.f;
    if (m < 2 * G) {
        const int ri = m >= G;
        const int g = m - ri * G;
        const int blk = k >= Hoff;
        const int hh = k - blk * Hoff;
        if (hh < H) {
            const float wr = Wr[(size_t)g * H + hh];
            const float wi = Wi[(size_t)g * H + hh];
            val = ri ? (blk ? wr : wi) : (blk ? -wi : wr);
        }
    }
    A[i] = f2bf(val);
}

// layer weights: 4 layers in one launch (blockIdx.y = l)
__global__ __launch_bounds__(256) void buildwL_k(
    const float* __restrict__ Wr0, const float* __restrict__ Wi0,
    unsigned short* __restrict__ A0)
{
    const int l = blockIdx.y;
    const float* Wr = Wr0 + (size_t)l * 65536;
    const float* Wi = Wi0 + (size_t)l * 65536;
    unsigned short* A = A0 + (size_t)l * 262144;
    const int i = blockIdx.x * 256 + threadIdx.x;
    const int m = i >> 9, k = i & 511;
    const int ri = m >= 256;
    const int g = m & 255;
    const int blk = k >> 8;
    const int hh = k & 255;
    const float wr = Wr[(size_t)g * 256 + hh];
    const float wi = Wi[(size_t)g * 256 + hh];
    const float val = ri ? (blk ? wr : wi) : (blk ? -wi : wr);
    A[i] = f2bf(val);
}

__global__ __launch_bounds__(256) void build_bias_k(
    const float* __restrict__ br, const float* __restrict__ bi,
    float* __restrict__ bias, int G)
{
    const int i = blockIdx.x * 256 + threadIdx.x;
    if (i < G) bias[i] = br[i];
    else if (i < 2 * G) bias[i] = bi[i - G];
}

__global__ __launch_bounds__(256) void build_biasL_k(
    const float* __restrict__ br0, const float* __restrict__ bi0,
    float* __restrict__ bias0)
{
    const int l = blockIdx.y;
    const int i = blockIdx.x * 256 + threadIdx.x;
    const float* br = br0 + l * 256;
    const float* bi = bi0 + l * 256;
    float* bias = bias0 + l * 512;
    if (i < 256) bias[i] = br[i];
    else bias[i] = bi[i - 256];
}

// ---------- encoder input pack: x (b,514,T,2) fp32 -> xp (b,T,1056) bf16 ----------
__global__ __launch_bounds__(256) void packx_k(const float* __restrict__ x,
                                               unsigned short* __restrict__ xp)
{
    const int t0 = blockIdx.x * 64, d0 = blockIdx.y * 64, b = blockIdx.z;
    __shared__ unsigned short tr_[64][72];
    __shared__ unsigned short ti_[64][72];
    const int tid = threadIdx.x;
    const int tp = tid & 31, dl0 = tid >> 5;
#pragma unroll
    for (int p = 0; p < 8; ++p) {
        const int d = dl0 + p * 8;
        const int gd = d0 + d;
        float4 v = make_float4(0.f, 0.f, 0.f, 0.f);
        if (gd < 514) v = *(const float4*)(x + (((size_t)b * 514 + gd) * 2048 + t0 + tp * 2) * 2);
        tr_[tp * 2 + 0][d] = f2bf(v.x); ti_[tp * 2 + 0][d] = f2bf(v.y);
        tr_[tp * 2 + 1][d] = f2bf(v.z); ti_[tp * 2 + 1][d] = f2bf(v.w);
    }
    __syncthreads();
    const int dc = tid & 7;
    const int kloc = d0 + dc * 8;
    if (kloc < 528) {
#pragma unroll
        for (int p = 0; p < 2; ++p) {
            const int t = (tid >> 3) + p * 32;
            const size_t rowb = ((size_t)b * 2048 + t0 + t) * 1056;
            *(short8*)&xp[rowb + kloc]       = *(const short8*)&tr_[t][dc * 8];
            *(short8*)&xp[rowb + 528 + kloc] = *(const short8*)&ti_[t][dc * 8];
        }
    }
}

// ---------- transpose planes (b,512,T) fp32 -> k-major (b,T,512) bf16 ----------
__global__ __launch_bounds__(256) void trz_k(const float* __restrict__ sf,
                                             unsigned short* __restrict__ dst)
{
    const int t0 = blockIdx.x * 64, k0 = blockIdx.y * 64, b = blockIdx.z;
    __shared__ unsigned short tile[64][72];
    const int tid = threadIdx.x;
    const int tp = tid & 31, kl0 = tid >> 5;
#pragma unroll
    for (int p = 0; p < 8; ++p) {
        const int kl = kl0 + p * 8;
        const float2 v = *(const float2*)(sf + ((size_t)b * 512 + k0 + kl) * 2048 + t0 + tp * 2);
        tile[tp * 2 + 0][kl] = f2bf(v.x);
        tile[tp * 2 + 1][kl] = f2bf(v.y);
    }
    __syncthreads();
    const int dc = tid & 7;
#pragma unroll
    for (int p = 0; p < 2; ++p) {
        const int t = (tid >> 3) + p * 32;
        *(short8*)&dst[((size_t)b * 2048 + t0 + t) * 512 + k0 + dc * 8] = *(const short8*)&tile[t][dc * 8];
    }
}

// ---------- bf16 MFMA GEMM (encoder/decoder): out = A * Bm^T + bias ----------
template<int MODE>
__global__ __launch_bounds__(256, 2) void mgemm_k(
    const unsigned short* __restrict__ A, const float* __restrict__ bias,
    const unsigned short* __restrict__ Bm, float* __restrict__ out,
    int M, int Kp)
{
    __shared__ unsigned short As[4096];  // [m 0..127][k 0..31]
    __shared__ unsigned short Bs[4096];  // [t 0..127][k 0..31]
    const int tid = threadIdx.x;
    const int w = tid >> 6, lane = tid & 63;
    const int m0 = blockIdx.x * 128, t0 = blockIdx.y * 128, b = blockIdx.z;
    const int wm = w & 1, wn = w >> 1;

    const unsigned short* Ab = A + (size_t)m0 * Kp;
    const unsigned short* Bb = Bm + ((size_t)b * 2048 + t0) * Kp;

    const int c0 = w * 64 + lane;
    const int r0 = c0 >> 2, q0 = (c0 & 3) * 8;
    const int c1 = c0 + 256;
    const int r1 = c1 >> 2, q1 = (c1 & 3) * 8;
    unsigned short* As0 = &As[(size_t)(w * 64) * 8];
    unsigned short* As1 = &As[(size_t)(w * 64 + 256) * 8];
    unsigned short* Bs0 = &Bs[(size_t)(w * 64) * 8];
    unsigned short* Bs1 = &Bs[(size_t)(w * 64 + 256) * 8];

    float4v acc[4][4];
#pragma unroll
    for (int i = 0; i < 4; ++i)
#pragma unroll
        for (int j = 0; j < 4; ++j) acc[i][j] = (float4v){0.f, 0.f, 0.f, 0.f};

    const int arow = wm * 64 + (lane & 15);
    const int brow = wn * 64 + (lane & 15);
    const int kq = (lane >> 4) * 8;

    for (int k0 = 0; k0 < Kp; k0 += 32) {
        ASYNC_COPY16(Ab + (size_t)r0 * Kp + k0 + q0, As0);
        ASYNC_COPY16(Ab + (size_t)r1 * Kp + k0 + q1, As1);
        ASYNC_COPY16(Bb + (size_t)r0 * Kp + k0 + q0, Bs0);
        ASYNC_COPY16(Bb + (size_t)r1 * Kp + k0 + q1, Bs1);
        __syncthreads();
        short8 af[4], bf[4];
#pragma unroll
        for (int i = 0; i < 4; ++i) af[i] = *(const short8*)&As[(arow + i * 16) * 32 + kq];
#pragma unroll
        for (int j = 0; j < 4; ++j) bf[j] = *(const short8*)&Bs[(brow + j * 16) * 32 + kq];
#pragma unroll
        for (int i = 0; i < 4; ++i)
#pragma unroll
            for (int j = 0; j < 4; ++j)
                acc[i][j] = __builtin_amdgcn_mfma_f32_16x16x32_bf16(af[i], bf[j], acc[i][j], 0, 0, 0);
        __syncthreads();
    }

    const int col = lane & 15;
    const int rq = (lane >> 4) * 4;
#pragma unroll
    for (int i = 0; i < 4; ++i) {
        const int mloc = wm * 64 + i * 16 + rq;
#pragma unroll
        for (int r = 0; r < 4; ++r) {
            const int m = m0 + mloc + r;
            if (MODE == 1 && m >= M) continue;
            const float bs = bias[m];
#pragma unroll
            for (int j = 0; j < 4; ++j) {
                const int t = t0 + wn * 64 + j * 16 + col;
                const float vv = acc[i][j][r] + bs;
                if (MODE == 0) {
                    out[((size_t)b * 512 + m) * 2048 + t] = vv;
                } else {
                    const int comp = m >= 514;
                    const int g = m - 514 * comp;
                    out[(((size_t)b * 514 + g) * 2048 + t) * 2 + comp] = vv;
                }
            }
        }
    }
}

// ---------- fused layer GEMM + residual + channel LayerNorm ----------
// R5: B staged DIRECTLY from t-major y planes (b,512,T bf16); the
// transpose happens on the LDS write (scalar b16, XOR-swizzled).
// Bs layout: flat [t 0..63][k 0..511], row stride 1024B, byte address
//   addr = t*1024 + (kbyte ^ mask(t)),  mask(t) = ((t&7)^((t>>3)&7))<<4.
// mask only touches bits 4-6: 16B fragments stay contiguous, map bijective.
// Stage writes: within a wave, (t>>3)&7 spreads the 8 lane-groups over
// 8 bank-quads (2-way sub-dword only). K-loop b128 reads: 16 t-rows ->
// 2-way (free). Eliminates tr_k<0> and the yp round-trip entirely.
__global__ __launch_bounds__(512, 2) void mgemmln_k(
    const unsigned short* __restrict__ A, const float* __restrict__ bias,
    const unsigned short* __restrict__ Bm, float* __restrict__ z,
    const float* __restrict__ gamr, const float* __restrict__ gami,
    const float* __restrict__ betr, const float* __restrict__ beti, int l)
{
    __shared__ unsigned short Bs[64][512];   // 64KB, swizzled (see above)
    __shared__ float biasS[512], gamS[512], betS[512];
    __shared__ float sred[8][64][2];
    __shared__ float sstat[2][64][2];
    const int tid = threadIdx.x;
    const int w = tid >> 6, lane = tid & 63;
    const int t0g = blockIdx.x * 64, b = blockIdx.y;
    unsigned char* BsB = (unsigned char*)&Bs[0][0];

    // ---- stage B from y planes, transpose-on-write ----
    {
        const unsigned short* ysrc = Bm + (size_t)b * 512 * 2048 + t0g;
        const int tseg = lane & 7;       // 8-t segment (t = tseg*8 + j)
        const int rloc = lane >> 3;      // row within the wave's octet
#pragma unroll
        for (int p = 0; p < 8; ++p) {
            const int krow = w * 8 + rloc + p * 64;
            const short8 v = *(const short8*)(ysrc + (size_t)krow * 2048 + tseg * 8);
#pragma unroll
            for (int j = 0; j < 8; ++j) {
                const int t = tseg * 8 + j;
                const int mask = (((t & 7) ^ ((t >> 3) & 7)) << 4);
                *(unsigned short*)(BsB + t * 1024 + ((krow * 2) ^ mask)) =
                    ((const unsigned short*)&v)[j];
            }
        }
        const int m = tid, g = m & 255, comp = m >> 8;
        biasS[m] = bias[m];
        gamS[m] = (comp ? gami : gamr)[l * 256 + g];
        betS[m] = (comp ? beti : betr)[l * 256 + g];
    }
    __syncthreads();

    // ---- K-loop: A direct from global (L2-resident), B from LDS ----
    float4v acc[4][4];
#pragma unroll
    for (int i = 0; i < 4; ++i)
#pragma unroll
        for (int j = 0; j < 4; ++j) acc[i][j] = (float4v){0.f, 0.f, 0.f, 0.f};

    const int brow = lane & 15;
    const int kq8 = (lane >> 4) * 8;                       // k-octet within 32
    const unsigned short* Ab = A + ((size_t)(w * 64 + brow)) * 512 + kq8;
    int baseB[4], maskB[4];
#pragma unroll
    for (int j = 0; j < 4; ++j) {
        const int t = j * 16 + brow;
        baseB[j] = t * 1024;
        maskB[j] = (((t & 7) ^ ((t >> 3) & 7)) << 4);
    }

#define LOADF(af_, bf_, k0_) do {                                              \
    _Pragma("unroll")                                                          \
    for (int i = 0; i < 4; ++i)                                                \
        af_[i] = *(const short8*)(Ab + (size_t)i * 16 * 512 + (k0_));          \
    _Pragma("unroll")                                                          \
    for (int j = 0; j < 4; ++j)                                                \
        bf_[j] = *(const short8*)(BsB + baseB[j] + ((((k0_) + kq8) * 2) ^ maskB[j])); \
} while (0)
#define MFMAS(af_, bf_) do {                                                   \
    _Pragma("unroll")                                                          \
    for (int i = 0; i < 4; ++i)                                                \
        _Pragma("unroll")                                                      \
        for (int j = 0; j < 4; ++j)                                            \
            acc[i][j] = __builtin_amdgcn_mfma_f32_16x16x32_bf16(af_[i], bf_[j], acc[i][j], 0, 0, 0); \
} while (0)

    {
        short8 afA[4], bfA[4], afB[4], bfB[4];
        LOADF(afA, bfA, 0);
#pragma unroll 1
        for (int kk = 0; kk < 16; kk += 2) {
            LOADF(afB, bfB, kk * 32 + 32);
            MFMAS(afA, bfA);
            if (kk + 2 < 16) LOADF(afA, bfA, kk * 32 + 64);
            MFMAS(afB, bfB);
        }
    }
#undef LOADF
#undef MFMAS

    // ---- epilogue: v = acc + bias + z_old, LN stats, normalize, write z ----
    const int q4 = (lane >> 4) * 4;
    float4 b4[4], g4[4], e4[4];
#pragma unroll
    for (int i = 0; i < 4; ++i) {
        const int m0 = w * 64 + i * 16 + q4;
        b4[i] = *(const float4*)&biasS[m0];
        g4[i] = *(const float4*)&gamS[m0];
        e4[i] = *(const float4*)&betS[m0];
    }

    float s1[4], s2[4];
#pragma unroll
    for (int j = 0; j < 4; ++j) { s1[j] = 0.f; s2[j] = 0.f; }
#pragma unroll
    for (int j = 0; j < 4; ++j) {
        const int t = t0g + j * 16 + brow;
#pragma unroll
        for (int i = 0; i < 4; ++i) {
            const int m = w * 64 + i * 16 + q4;
            const float* zp = &z[((size_t)b * 512 + m) * 2048 + t];
            const float bb[4] = {b4[i].x, b4[i].y, b4[i].z, b4[i].w};
#pragma unroll
            for (int r = 0; r < 4; ++r) {
                const float v = acc[i][j][r] + bb[r] + zp[(size_t)r * 2048];
                acc[i][j][r] = v;
                s1[j] += v; s2[j] += v * v;
            }
        }
    }
#pragma unroll
    for (int j = 0; j < 4; ++j) {
        s1[j] += __shfl_xor(s1[j], 16); s2[j] += __shfl_xor(s2[j], 16);
        s1[j] += __shfl_xor(s1[j], 32); s2[j] += __shfl_xor(s2[j], 32);
    }
    if (lane < 16) {
#pragma unroll
        for (int j = 0; j < 4; ++j) {
            sred[w][j * 16 + lane][0] = s1[j];
            sred[w][j * 16 + lane][1] = s2[j];
        }
    }
    __syncthreads();
    if (tid < 128) {
        const int t = tid & 63, comp = tid >> 6;
        float S1 = 0.f, S2 = 0.f;
#pragma unroll
        for (int w2 = 0; w2 < 4; ++w2) {
            S1 += sred[comp * 4 + w2][t][0];
            S2 += sred[comp * 4 + w2][t][1];
        }
        const float mn = S1 * (1.f / 256.f);
        const float var = S2 * (1.f / 256.f) - mn * mn;
        sstat[comp][t][0] = mn;
        sstat[comp][t][1] = rsqrtf(var + 1e-5f);
    }
    __syncthreads();
    const int comp = w >> 2;
#pragma unroll
    for (int j = 0; j < 4; ++j) {
        const int tl = j * 16 + brow;
        const float mn = sstat[comp][tl][0], rs = sstat[comp][tl][1];
        const int t = t0g + tl;
#pragma unroll
        for (int i = 0; i < 4; ++i) {
            const int m = w * 64 + i * 16 + q4;
            float* zp = &z[((size_t)b * 512 + m) * 2048 + t];
            const float gg[4] = {g4[i].x, g4[i].y, g4[i].z, g4[i].w};
            const float ee[4] = {e4[i].x, e4[i].y, e4[i].z, e4[i].w};
#pragma unroll
            for (int r = 0; r < 4; ++r)
                zp[(size_t)r * 2048] = (acc[i][j][r] - mn) * rs * gg[r] + ee[r];
        }
    }
}

// ---------- S4D diagonal SSM scan + D-skip + gelu -> bf16 planes ----------
// R3 design (verified): LDS-resident u, DPP quad-perm reduce, ys aliased
// over vsh, 34.8KB LDS.
__global__ __launch_bounds__(256, 4) void s4scan_k(
    const float* __restrict__ z, unsigned short* __restrict__ y,
    const float* __restrict__ log_dt, const float* __restrict__ log_A_real,
    const float* __restrict__ A_imag, const float* __restrict__ C_r,
    const float* __restrict__ C_i, const float* __restrict__ Dsk, int l)
{
    const int h = blockIdx.x, b = blockIdx.y;
    const int tid = threadIdx.x;
    const int lane = tid & 63, wv = tid >> 6;
    __shared__ float2 wsh[32], csh[32];
    __shared__ float dsh;
    __shared__ float2 us[64][33];
    __shared__ __align__(16) unsigned char uni[64 * 33 * 8];
    float2 (*vsh2)[33] = (float2(*)[33])uni;
    float2 (*ys)[33]   = (float2(*)[33])uni;

    if (tid < 32) {
        const size_t pidx = ((size_t)l * 256 + h) * 32 + tid;
        const float dt = __expf(log_dt[l * 256 + h]);
        const float Ar = -__expf(log_A_real[pidx]);
        const float Ai = A_imag[pidx];
        const float er = __expf(Ar * dt);
        float sv, cv;
        __sincosf(Ai * dt, &sv, &cv);
        const float wr = er * cv, wi = er * sv;
        const float den = 1.f / (Ar * Ar + Ai * Ai);
        const float nr = wr - 1.f, ni = wi;
        const float qr = (nr * Ar + ni * Ai) * den;
        const float qi = (ni * Ar - nr * Ai) * den;
        const float cr = C_r[pidx], ci = C_i[pidx];
        wsh[tid] = make_float2(wr, wi);
        csh[tid] = make_float2(cr * qr - ci * qi, cr * qi + ci * qr);
    }
    if (tid == 32) dsh = Dsk[l * 256 + h];

    const int c0q = tid >> 2, t0q = (tid & 3) * 8;
    {
        const float* zrp = z + ((size_t)b * 512 + h) * 2048 + tid * 8;
        const float* zip = zrp + 256 * 2048;
        const float4 r0 = *(const float4*)zrp, r1 = *(const float4*)(zrp + 4);
        const float4 i0 = *(const float4*)zip, i1 = *(const float4*)(zip + 4);
        float2* up = &us[c0q][t0q];
        up[0] = make_float2(r0.x, i0.x); up[1] = make_float2(r0.y, i0.y);
        up[2] = make_float2(r0.z, i0.z); up[3] = make_float2(r0.w, i0.w);
        up[4] = make_float2(r1.x, i1.x); up[5] = make_float2(r1.y, i1.y);
        up[6] = make_float2(r1.z, i1.z); up[7] = make_float2(r1.w, i1.w);
    }
    __syncthreads();

    // ---- sweep 1: chunk-local finals + butterfly -> exclusive states ----
    {
        float2 w8[8], x8[8];
#pragma unroll
        for (int j = 0; j < 8; ++j) {
            w8[j] = wsh[wv * 8 + j];
            x8[j] = make_float2(0.f, 0.f);
        }
#pragma unroll 8
        for (int tt = 0; tt < 32; ++tt) {
            const float2 u = us[lane][tt];
#pragma unroll
            for (int j = 0; j < 8; ++j) {
                const float nxr = __builtin_fmaf(w8[j].x, x8[j].x, __builtin_fmaf(-w8[j].y, x8[j].y, u.x));
                const float nxi = __builtin_fmaf(w8[j].x, x8[j].y, __builtin_fmaf(w8[j].y, x8[j].x, u.y));
                x8[j].x = nxr; x8[j].y = nxi;
            }
        }
#pragma unroll
        for (int j = 0; j < 8; ++j) {
            float fr = w8[j].x, fi = w8[j].y;
#pragma unroll
            for (int s = 0; s < 5; ++s) { const float a2 = fr * fr - fi * fi, b2 = 2.f * fr * fi; fr = a2; fi = b2; }
            float qrv = x8[j].x, qiv = x8[j].y, pr = fr, pi = fi;
#pragma unroll
            for (int s = 0; s < 6; ++s) {
                const int d = 1 << s;
                const float sr = __shfl_up(qrv, (unsigned)d);
                const float si = __shfl_up(qiv, (unsigned)d);
                if (lane >= d) {
                    qrv += pr * sr - pi * si;
                    qiv += pr * si + pi * sr;
                }
                const float a2 = pr * pr - pi * pi, b2 = 2.f * pr * pi;
                pr = a2; pi = b2;
            }
            float vr = __shfl_up(qrv, 1u);
            float vi = __shfl_up(qiv, 1u);
            if (lane == 0) { vr = 0.f; vi = 0.f; }
            vsh2[lane][wv * 8 + j] = make_float2(vr, vi);
        }
    }
    __syncthreads();

    // ---- sweep 2: single 8-mode pass, DPP reduce, ys written once ----
    {
        const int q = tid & 3;
        float2 w8[8], c8[8], s8[8];
#pragma unroll
        for (int j = 0; j < 8; ++j) {
            const int n = q * 8 + j;
            w8[j] = wsh[n];
            c8[j] = csh[n];
            s8[j] = vsh2[c0q][n];
        }
        __syncthreads();  // vsh2 fully in regs; ys may now overwrite it
#pragma unroll 4
        for (int tt = 0; tt < 32; ++tt) {
            const float2 u = us[c0q][tt];
            float pyr = 0.f, pyi = 0.f;
#pragma unroll
            for (int j = 0; j < 8; ++j) {
                const float nsr = __builtin_fmaf(w8[j].x, s8[j].x, __builtin_fmaf(-w8[j].y, s8[j].y, u.x));
                const float nsi = __builtin_fmaf(w8[j].x, s8[j].y, __builtin_fmaf(w8[j].y, s8[j].x, u.y));
                s8[j].x = nsr; s8[j].y = nsi;
                pyr = __builtin_fmaf(c8[j].x, nsr, __builtin_fmaf(-c8[j].y, nsi, pyr));
                pyi = __builtin_fmaf(c8[j].x, nsi, __builtin_fmaf(c8[j].y, nsr, pyi));
            }
            pyr = dppadd<DPP_XOR1>(pyr); pyr = dppadd<DPP_XOR2>(pyr);
            pyi = dppadd<DPP_XOR1>(pyi); pyi = dppadd<DPP_XOR2>(pyi);
            if (q == 0) ys[c0q][tt] = make_float2(pyr, pyi);
        }
    }
    __syncthreads();

    // ---- final: D-skip + gelu + bf16 pack + coalesced stores ----
    {
        const float dv = dsh;
        unsigned short* yrp = y + ((size_t)b * 512 + h) * 2048 + tid * 8;
        unsigned short* yip = yrp + 256 * 2048;
        short8 vr8, vi8;
#pragma unroll
        for (int j = 0; j < 8; ++j) {
            const float2 yv = ys[c0q][t0q + j];
            const float2 uv = us[c0q][t0q + j];
            ((unsigned short*)&vr8)[j] = f2bf(gelu_tanh(__builtin_fmaf(dv, uv.x, yv.x)));
            ((unsigned short*)&vi8)[j] = f2bf(gelu_tanh(__builtin_fmaf(dv, uv.y, yv.y)));
        }
        *(short8*)yrp = vr8;
        *(short8*)yip = vi8;
    }
}

extern "C" void kernel_launch(void* const* d_in, const int* in_sizes, int n_in,
                              void* d_out, int out_size, void* d_ws, size_t ws_size,
                              hipStream_t stream)
{
    const float* x        = (const float*)d_in[0];
    const float* enc_Wr   = (const float*)d_in[1];
    const float* enc_Wi   = (const float*)d_in[2];
    const float* enc_br   = (const float*)d_in[3];
    const float* enc_bi   = (const float*)d_in[4];
    const float* log_dt   = (const float*)d_in[5];
    const float* log_A_r  = (const float*)d_in[6];
    const float* A_imag   = (const float*)d_in[7];
    const float* C_r      = (const float*)d_in[8];
    const float* C_i      = (const float*)d_in[9];
    const float* Dp       = (const float*)d_in[10];
    const float* out_Wr   = (const float*)d_in[11];
    const float* out_Wi   = (const float*)d_in[12];
    const float* out_br   = (const float*)d_in[13];
    const float* out_bi   = (const float*)d_in[14];
    const float* ln_gr    = (const float*)d_in[15];
    const float* ln_gi    = (const float*)d_in[16];
    const float* ln_br    = (const float*)d_in[17];
    const float* ln_bi    = (const float*)d_in[18];
    const float* dec_Wr   = (const float*)d_in[19];
    const float* dec_Wi   = (const float*)d_in[20];
    const float* dec_br   = (const float*)d_in[21];
    const float* dec_bi   = (const float*)d_in[22];

    // ---- workspace layout (bytes) ----
    uint8_t* W = (uint8_t*)d_ws;
    float* z             = (float*)W;                       // 33,554,432
    unsigned short* zp   = (unsigned short*)(W + 33554432); // 16,777,216
    unsigned short* A_enc= (unsigned short*)(W + 50331648); // 512x1056x2  = 1,081,344
    unsigned short* A_lay= (unsigned short*)(W + 51412992); // 4x512x512x2 = 2,097,152
    unsigned short* A_dec= (unsigned short*)(W + 53510144); // 1152x512x2  = 1,179,648
    float* b_enc         = (float*)(W + 54689792);          // 512 f
    float* b_lay         = (float*)(W + 54691840);          // 2048 f
    float* b_dec         = (float*)(W + 54700032);          // 1028 f

    // ---- d_out doubles as scratch ----
    unsigned short* y   = (unsigned short*)((uint8_t*)d_out + 33554432);   // 16,777,216
    unsigned short* xp  = (unsigned short*)d_out;  // 34,603,008; dead after encoder GEMM

    // ---- build weights/biases ----
    buildw_k<<<2112, 256, 0, stream>>>(enc_Wr, enc_Wi, A_enc, 256, 514, 528, 1056, 512);
    buildwL_k<<<dim3(1024, 4), 256, 0, stream>>>(out_Wr, out_Wi, A_lay);
    buildw_k<<<2304, 256, 0, stream>>>(dec_Wr, dec_Wi, A_dec, 514, 256, 256, 512, 1152);
    build_bias_k<<<2, 256, 0, stream>>>(enc_br, enc_bi, b_enc, 256);
    build_biasL_k<<<dim3(2, 4), 256, 0, stream>>>(out_br, out_bi, b_lay);
    build_bias_k<<<5, 256, 0, stream>>>(dec_br, dec_bi, b_dec, 514);

    // ---- encoder: pack x -> xp, GEMM -> z ----
    packx_k<<<dim3(32, 9, 8), 256, 0, stream>>>(x, xp);
    mgemm_k<0><<<dim3(4, 16, 8), 256, 0, stream>>>(A_enc, b_enc, xp, z, 512, 1056);

    // ---- layers: scan -> fused transpose+GEMM+residual+LN ----
    for (int l = 0; l < 4; ++l) {
        s4scan_k<<<dim3(256, 8), 256, 0, stream>>>(z, y, log_dt, log_A_r, A_imag, C_r, C_i, Dp, l);
        mgemmln_k<<<dim3(32, 8), 512, 0, stream>>>(A_lay + (size_t)l * 262144,
                                                   b_lay + l * 512, y, z,
                                                   ln_gr, ln_gi, ln_br, ln_bi, l);
    }

    // ---- decoder: z -> zp, GEMM -> d_out interleaved ----
    trz_k<<<dim3(32, 8, 8), 256, 0, stream>>>(z, zp);
    mgemm_k<1><<<dim3(9, 16, 8), 256, 0, stream>>>(A_dec, b_dec, zp, (float*)d_out, 1028, 512);
}